// Round 4
// baseline (554.814 us; speedup 1.0000x reference)
//
#include <hip/hip_runtime.h>
#include <stdint.h>

typedef unsigned int u32;
typedef unsigned long long u64;
typedef unsigned short u16b;
typedef __attribute__((ext_vector_type(8))) _Float16 half8;  // 8 fp16 = 4 VGPR (MFMA A/B frag)
typedef __attribute__((ext_vector_type(4))) float v4f;       // MFMA C/D frag

constexpr int NP = 16384;   // points per batch
// ---- fixed float-region offsets (in floats) ----
constexpr int W0T = 0;        // [8][64] fp32 (L0 stays VALU)
constexpr int B0F = 16896, B1F = 16960, B2F = 17024, B3F = 17088, B4F = 17216;
constexpr int GFO = 18240;    // gf  [16][1024]
constexpr int GCFO = 34624;   // gcf [4][1024]
constexpr int OF1O = 38720;   // of1 [16][512]
constexpr int GR1O = 46912;   // gr1 [512]
constexpr int FIXED_FLOATS = 47424;
constexpr u32 FIXED_BYTES = FIXED_FLOATS * 4;   // 189696 B

struct __align__(16) f4 { float x, y, z, w; };

// fp16 split-2 with scaled low part: x ~= h + 2^-11 * l, both fp16-normal.
__device__ __forceinline__ void split2(float x, u16b& h, u16b& l){
  _Float16 hh = (_Float16)x;                 // v_cvt_f16_f32 (RNE)
  float r = (x - (float)hh) * 2048.f;        // exact subtract, exact *2^11
  _Float16 ll = (_Float16)r;
  union { _Float16 f; u16b u; } a, b; a.f = hh; b.f = ll;
  h = a.u; l = b.u;
}

__device__ __forceinline__ void fma4(f4& c, float s, const f4& a){
  c.x = fmaf(s, a.x, c.x); c.y = fmaf(s, a.y, c.y);
  c.z = fmaf(s, a.z, c.z); c.w = fmaf(s, a.w, c.w);
}

// row swizzle: phys row = S ^ ((S>>3)&7). Bijective (triangular). Makes the
// MFMA-D-layout b16 frag stores conflict-free and keeps reads bijective.
__device__ __forceinline__ int swz(int S){ return S ^ ((S >> 3) & 7); }

// ---------------- prep ----------------
// Wb  (L4, fp16x2): [s][kc4][nt][lane][j]   u16 addr = s*131072 + kc*32768 + nt*512 + L*8 + j
// Wb1 (L1, fp16x2): [s][kc2][cb4][lane][j]  u16 addr = s*4096 + kc*2048 + cb*512 + slot*8 + j
// Wb2 (L2): same as Wb1.  Wb3 (L3): [s][kc2][cb8][lane][j]  plane 8192 u16.
__global__ __launch_bounds__(256) void k_prep(
    const float* __restrict__ wl0, const float* __restrict__ wl1, const float* __restrict__ wl2,
    const float* __restrict__ wl3, const float* __restrict__ wl4,
    const float* __restrict__ bl0, const float* __restrict__ bl1, const float* __restrict__ bl2,
    const float* __restrict__ bl3, const float* __restrict__ bl4,
    float* __restrict__ wsf, u32 pmax_off, u32 gmax_off, u32 wb_off, int P, int G)
{
  int tid = blockIdx.x * 256 + threadIdx.x;            // grid 1024 -> 262144 threads
  u64* pmax = (u64*)((char*)wsf + pmax_off);
  u32* gmax = (u32*)((char*)wsf + gmax_off);
  if (tid < P * 16384) pmax[tid] = 0ull;
  if (tid < G * 4096)  gmax[tid] = 0u;
  if (tid < 131072){                                   // W5 split -> Wb (2 planes)
    int ch = tid >> 7, k = tid & 127;
    float x = wl4[tid];
    u16b h, l; split2(x, h, l);
    int kc = k >> 5, q = (k >> 3) & 3, j = k & 7, nt = ch >> 4;
    u32 base = (u32)kc*32768u + (u32)nt*512u + (u32)(((ch & 15) | (q << 4)) * 8 + j);
    u16b* wb = (u16b*)((char*)wsf + wb_off);
    wb[base] = h; wb[131072u + base] = l;
  }
  if (tid < 4096){                                     // W1 split -> Wb1
    int o = tid >> 6, c = tid & 63;
    float x = wl1[tid];
    u16b h, l; split2(x, h, l);
    u32 a = (u32)((c>>5)*2048 + (o>>4)*512 + (((o&15) | (((c>>3)&3)<<4)) << 3) + (c&7));
    u16b* p = (u16b*)((char*)wsf + wb_off + 524288u);
    p[a] = h; p[4096u + a] = l;
  }
  if (tid < 4096){                                     // W2 split -> Wb2
    int o = tid >> 6, c = tid & 63;
    float x = wl2[tid];
    u16b h, l; split2(x, h, l);
    u32 a = (u32)((c>>5)*2048 + (o>>4)*512 + (((o&15) | (((c>>3)&3)<<4)) << 3) + (c&7));
    u16b* p = (u16b*)((char*)wsf + wb_off + 524288u + 16384u);
    p[a] = h; p[4096u + a] = l;
  }
  if (tid < 8192){                                     // W3 split -> Wb3
    int o = tid >> 6, c = tid & 63;                    // o 0..127
    float x = wl3[tid];
    u16b h, l; split2(x, h, l);
    u32 a = (u32)((c>>5)*4096 + (o>>4)*512 + (((o&15) | (((c>>3)&3)<<4)) << 3) + (c&7));
    u16b* p = (u16b*)((char*)wsf + wb_off + 524288u + 32768u);
    p[a] = h; p[8192u + a] = l;
  }
  if (tid < 512){ int k = tid >> 6, o = tid & 63;
    wsf[W0T + tid] = (k < 7) ? wl0[o*7 + k] : 0.f; }
  if (tid < 64)   wsf[B0F + tid] = bl0[tid];
  if (tid < 64)   wsf[B1F + tid] = bl1[tid];
  if (tid < 64)   wsf[B2F + tid] = bl2[tid];
  if (tid < 128)  wsf[B3F + tid] = bl3[tid];
  if (tid < 1024) wsf[B4F + tid] = bl4[tid];
}

// 4pt x 4ch micro-tile for L0 (K=7; acts from LDS, weights L2-resident)
template<int K, int OSTR>
__device__ __forceinline__ void gemm4(const float* Ain, const float* __restrict__ Wt,
                                      int pt4, int o4, f4 (&acc)[4])
{
  #pragma unroll
  for (int oi = 0; oi < 4; ++oi) acc[oi] = f4{0.f,0.f,0.f,0.f};
  #pragma unroll
  for (int k = 0; k < K; ++k){
    f4 a = *(const f4*)(Ain + k*64 + pt4);
    f4 w = *(const f4*)(Wt + k*OSTR + o4);
    fma4(acc[0], w.x, a); fma4(acc[1], w.y, a);
    fma4(acc[2], w.z, a); fma4(acc[3], w.w, a);
  }
}

// one 64->64 MFMA layer (fp16 split-2, 3-term). Fin/Fout: frag buffers
// [plane][frag = m*2+kc][phys row 64][j 8], plane stride 4096 u16.
__device__ __forceinline__ void layer64(const u16b* Fin, u16b* Fout,
    const u16b* __restrict__ wbL, const float* __restrict__ wsf, int bofs,
    int w, int L, int sigL)
{
  v4f D0[4], D1[4];
  #pragma unroll
  for (int m = 0; m < 4; ++m){ D0[m] = (v4f)(0.f); D1[m] = (v4f)(0.f); }
  #pragma unroll
  for (int kc = 0; kc < 2; ++kc){
    const u16b* wp = wbL + (u32)(kc*2048 + w*512 + L*8);
    half8 b0 = *(const half8*)(wp);
    half8 b1 = *(const half8*)(wp + 4096);
    #pragma unroll
    for (int m = 0; m < 4; ++m){
      const u16b* fa = Fin + (u32)((m*2 + kc)*512 + sigL*8);
      half8 a0 = *(const half8*)(fa);
      half8 a1 = *(const half8*)(fa + 4096);
      D0[m] = __builtin_amdgcn_mfma_f32_16x16x32_f16(a0, b0, D0[m], 0, 0, 0);
      D1[m] = __builtin_amdgcn_mfma_f32_16x16x32_f16(a1, b0, D1[m], 0, 0, 0);
      D1[m] = __builtin_amdgcn_mfma_f32_16x16x32_f16(a0, b1, D1[m], 0, 0, 0);
    }
  }
  // epilogue: combine, bias, relu, split2, frag-store (D layout: ch=L&15 fixed, 4 pts/lane)
  int ch = (w << 4) + (L & 15);
  float bias = wsf[bofs + ch];
  int kcO = ch >> 5, q = (ch >> 3) & 3, j = ch & 7;
  int rowb = (L >> 4) << 2;                  // pt&15 base
  #pragma unroll
  for (int m = 0; m < 4; ++m){
    #pragma unroll
    for (int r = 0; r < 4; ++r){
      float v = fmaxf(fmaf(D1[m][r], 0x1p-11f, D0[m][r]) + bias, 0.f);
      u16b h, l; split2(v, h, l);
      int Sp = swz((rowb + r) | (q << 4));
      u32 a = (u32)((m*2 + kcO)*512 + Sp*8 + j);
      Fout[a] = h; Fout[4096u + a] = l;
    }
  }
}

// ---------------- fused local MLP: L0 fp32 VALU, L1-L4 fp16-split2 MFMA ----------------
// LDS 32768 B; __launch_bounds__(256,3): request 3 waves/EU (= 3 blocks/CU).
// Occupancy was pinned at the declared 2 across all resource profiles (r1-r3) ->
// the waves-per-EU attribute is the binding limit, not LDS/VGPR. Register cap at
// 3 waves/EU is ~170; peak usage ~96 arch + 48 acc (L3 restructured below).
__global__ __launch_bounds__(256, 3) void k_main(const float* __restrict__ pts,
    const float* __restrict__ wsf,
    const u16b* __restrict__ wb,  const u16b* __restrict__ wb1,
    const u16b* __restrict__ wb2, const u16b* __restrict__ wb3,
    u64* __restrict__ pmax, u32* __restrict__ gmax,
    int pmask, int gmask)
{
  __shared__ __align__(16) float sB[8192];     // 32768 B exactly
  u16b* LB = (u16b*)sB;
  float* A0F = sB + 4096;                      // inside FB region
  const int t = threadIdx.x;
  const int b = blockIdx.x >> 8;
  const int tile = blockIdx.x & 255;
  const int n0 = tile * 64;
  const int w = t >> 6;            // wave id 0..3
  const int L = t & 63;
  const int sigL = swz(L);
  const int qb = (L >> 4) << 2;    // my D-row quad base

  u64* gmS = (u64*)(sB + 4544);                // inside FB region, after A0F
  if (t < 4) gmS[t] = 0ull;
  for (int e = t; e < 7*64; e += 256)
    A0F[e] = pts[(b*7 + (e >> 6))*NP + n0 + (e & 63)];
  __syncthreads();   // s1

  // per-point group id (argmax ch 3..6, first occurrence) -> 64-bit masks
  if (t < 64){
    float v = A0F[3*64 + t]; int gi = 0;
    float u1 = A0F[4*64 + t]; if (u1 > v){ v = u1; gi = 1; }
    float u2 = A0F[5*64 + t]; if (u2 > v){ v = u2; gi = 2; }
    float u3 = A0F[6*64 + t]; if (u3 > v){ v = u3; gi = 3; }
    atomicOr(&gmS[gi], 1ull << t);
  }

  // ---- L0 (VALU fp32) -> FA frag store (FA disjoint from A0F/gmS) ----
  const int pt4 = (t & 15) << 2, o4 = (t >> 4) << 2;
  f4 acc4[4];
  gemm4<7,64>(A0F, wsf + W0T, pt4, o4, acc4);
  {
    const int kc0 = o4 >> 5, q0 = (o4 >> 3) & 3, j0 = o4 & 7;
    #pragma unroll
    for (int jj = 0; jj < 4; ++jj){
      int pt = pt4 + jj; int m = pt >> 4;
      int Sp = swz((pt & 15) | (q0 << 4));
      u16b hh[4], ll[4];
      #pragma unroll
      for (int oi = 0; oi < 4; ++oi){
        float v = fmaxf(((const float*)&acc4[oi])[jj] + wsf[B0F + o4 + oi], 0.f);
        split2(v, hh[oi], ll[oi]);
      }
      u32 a = (u32)((m*2 + kc0)*512 + Sp*8 + j0);
      uint2 ph, pl;
      ph.x = (u32)hh[0] | ((u32)hh[1] << 16); ph.y = (u32)hh[2] | ((u32)hh[3] << 16);
      pl.x = (u32)ll[0] | ((u32)ll[1] << 16); pl.y = (u32)ll[2] | ((u32)ll[3] << 16);
      *(uint2*)(LB + a) = ph; *(uint2*)(LB + 4096u + a) = pl;
    }
  }
  __syncthreads();   // s2 (FA ready + masks done)

  // ggpack: 2-bit group id for each of my 16 D-slots (i = m*4+r -> pt = m*16+qb+r)
  u32 g1lo = (u32)gmS[1], g1hi = (u32)(gmS[1] >> 32);
  u32 g2lo = (u32)gmS[2], g2hi = (u32)(gmS[2] >> 32);
  u32 g3lo = (u32)gmS[3], g3hi = (u32)(gmS[3] >> 32);
  u32 ggpack = 0;
  #pragma unroll
  for (int i = 0; i < 16; ++i){
    int m = i >> 2, r = i & 3;
    int sh = ((m & 1) << 4) + qb + r;          // pt&31
    u32 b1 = ((m < 2 ? g1lo : g1hi) >> sh) & 1u;
    u32 b2 = ((m < 2 ? g2lo : g2hi) >> sh) & 1u;
    u32 b3 = ((m < 2 ? g3lo : g3hi) >> sh) & 1u;
    u32 g = b1 + (b2 << 1) + (b3 << 1) + b3;   // 0..3, one-hot source
    ggpack |= g << (2*i);
  }
  __syncthreads();   // s2b (all gmS reads done; FB region may now be overwritten)

  layer64(LB, LB + 8192, wb1, wsf, B1F, w, L, sigL);   // L1: FA -> FB
  __syncthreads();   // s3
  layer64(LB + 8192, LB, wb2, wsf, B2F, w, L, sigL);   // L2: FB -> FA
  __syncthreads();   // s4

  // ---- L3 (64->128): FA -> regs; wave w owns ch-blocks 2w, 2w+1, processed
  // SEQUENTIALLY with immediate fp32 fold -> peak accumulators 48 (was 64) ----
  v4f Ef[2][4];
  #pragma unroll
  for (int c = 0; c < 2; ++c){
    v4f D0[4], D1[4];
    #pragma unroll
    for (int m = 0; m < 4; ++m){ D0[m] = (v4f)(0.f); D1[m] = (v4f)(0.f); }
    #pragma unroll
    for (int kc = 0; kc < 2; ++kc){
      const u16b* wp = wb3 + (u32)(kc*4096 + (w*2 + c)*512 + L*8);
      half8 b0 = *(const half8*)(wp);
      half8 b1 = *(const half8*)(wp + 8192);
      #pragma unroll
      for (int m = 0; m < 4; ++m){
        const u16b* fa = LB + (u32)((m*2 + kc)*512 + sigL*8);
        half8 a0 = *(const half8*)(fa);
        half8 a1 = *(const half8*)(fa + 4096);
        D0[m] = __builtin_amdgcn_mfma_f32_16x16x32_f16(a0, b0, D0[m], 0, 0, 0);
        D1[m] = __builtin_amdgcn_mfma_f32_16x16x32_f16(a1, b0, D1[m], 0, 0, 0);
        D1[m] = __builtin_amdgcn_mfma_f32_16x16x32_f16(a0, b1, D1[m], 0, 0, 0);
      }
    }
    #pragma unroll
    for (int m = 0; m < 4; ++m)
      #pragma unroll
      for (int r = 0; r < 4; ++r)
        Ef[c][m][r] = fmaf(D1[m][r], 0x1p-11f, D0[m][r]);
  }
  __syncthreads();   // s5 (all FA reads complete; F4 may overwrite FA+FB)

  // store F4 (planes 0 / 8192), frag = m*4 + (cb>>1)
  #pragma unroll
  for (int c = 0; c < 2; ++c){
    int cb = w*2 + c;
    int ch = (cb << 4) + (L & 15);
    float bias = wsf[B3F + ch];
    int kc4 = cb >> 1, q = (ch >> 3) & 3, j = ch & 7;
    #pragma unroll
    for (int m = 0; m < 4; ++m){
      #pragma unroll
      for (int r = 0; r < 4; ++r){
        float v = fmaxf(Ef[c][m][r] + bias, 0.f);
        u16b h, l; split2(v, h, l);
        int Sp = swz((qb + r) | (q << 4));
        u32 a = (u32)((m*4 + kc4)*512 + Sp*8 + j);
        LB[a] = h; LB[8192u + a] = l;
      }
    }
  }
  __syncthreads();   // s6 (F4 ready)

  u64* pslot = pmax + (size_t)(tile & pmask)*(16*1024) + b*1024;
  u32* gslot = gmax + (size_t)(tile & gmask)*4096;
  const char* wbc = (const char*)wb;
  const u32 bvo = (u32)L * 16u;

  // ---- L4: 16 N-tiles/wave; 3-term fp16-split2 MFMA; B-frags software-pipelined ----
  half8 bh, bl;
  {
    u32 bofs = ((u32)(w << 4)) * 1024u + bvo;        // (nt = w*16, kc = 0)
    bh = *(const half8*)(wbc +           bofs);
    bl = *(const half8*)(wbc + 262144u + bofs);
  }
  for (int nti = 0; nti < 16; ++nti){
    const int nt = (w << 4) + nti;
    float bias = wsf[B4F + (nt << 4) + (L & 15)];    // issue early
    v4f D0[4], D1[4];
    #pragma unroll
    for (int m = 0; m < 4; ++m){ D0[m] = (v4f)(0.f); D1[m] = (v4f)(0.f); }
    #pragma unroll
    for (int kc = 0; kc < 4; ++kc){
      half8 cb0 = bh, cb1 = bl;
      {
        int knext = (kc == 3) ? 0 : kc + 1;
        int ntn   = (kc == 3) ? nt + 1 : nt;
        u32 bofs = (u32)knext*65536u + (u32)ntn*1024u + bvo;
        bh = *(const half8*)(wbc +           bofs);
        bl = *(const half8*)(wbc + 262144u + bofs);
      }
      #pragma unroll
      for (int m = 0; m < 4; ++m){
        const u16b* fb = LB + (u32)((m*4 + kc)*512 + sigL*8);
        half8 a0 = *(const half8*)(fb);
        half8 a1 = *(const half8*)(fb + 8192);
        D0[m] = __builtin_amdgcn_mfma_f32_16x16x32_f16(a0, cb0, D0[m], 0, 0, 0);
        D1[m] = __builtin_amdgcn_mfma_f32_16x16x32_f16(a1, cb0, D1[m], 0, 0, 0);
        D1[m] = __builtin_amdgcn_mfma_f32_16x16x32_f16(a0, cb1, D1[m], 0, 0, 0);
      }
    }
    // epilogue: combine splits, bias+relu, per-lane argmax, group-masked maxes
    float mx = 0.f; int mi = 0;
    float gm0 = 0.f, gm1 = 0.f, gm2 = 0.f, gm3 = 0.f;
    #pragma unroll
    for (int m = 0; m < 4; ++m){
      #pragma unroll
      for (int r = 0; r < 4; ++r){
        int i = m*4 + r;
        float v = fmaxf(fmaf(D1[m][r], 0x1p-11f, D0[m][r]) + bias, 0.f);
        int pidx = n0 + m*16 + qb + r;
        if (i == 0){ mx = v; mi = pidx; }
        else if (v > mx){ mx = v; mi = pidx; }
        u32 g = (ggpack >> (2*i)) & 3u;
        gm0 = fmaxf(gm0, (g == 0u) ? v : 0.f);
        gm1 = fmaxf(gm1, (g == 1u) ? v : 0.f);
        gm2 = fmaxf(gm2, (g == 2u) ? v : 0.f);
        gm3 = fmaxf(gm3, (g == 3u) ? v : 0.f);
      }
    }
    #pragma unroll
    for (int s = 16; s <= 32; s <<= 1){
      float m2 = __shfl_xor(mx, s);
      int  i2  = __shfl_xor(mi, s);
      if (m2 > mx || (m2 == mx && i2 < mi)){ mx = m2; mi = i2; }
      gm0 = fmaxf(gm0, __shfl_xor(gm0, s));
      gm1 = fmaxf(gm1, __shfl_xor(gm1, s));
      gm2 = fmaxf(gm2, __shfl_xor(gm2, s));
      gm3 = fmaxf(gm3, __shfl_xor(gm3, s));
    }
    if (L < 16){
      int ch = (nt << 4) + L;
      u64 pk = ((u64)__float_as_uint(mx) << 32) | (u64)(0xFFFFFFFFu - (u32)mi);
      atomicMax(pslot + ch, pk);
      if (gm0 > 0.f) atomicMax(gslot + ch,        __float_as_uint(gm0));
      if (gm1 > 0.f) atomicMax(gslot + 1024 + ch, __float_as_uint(gm1));
      if (gm2 > 0.f) atomicMax(gslot + 2048 + ch, __float_as_uint(gm2));
      if (gm3 > 0.f) atomicMax(gslot + 3072 + ch, __float_as_uint(gm3));
    }
  }
}

// ---------------- fold slots; emit max_indices (fp32) + gf + gcf ----------------
__global__ __launch_bounds__(256) void k_reduce(float* __restrict__ wsf, float* __restrict__ out,
                                                u32 pmax_off, u32 gmax_off, int P, int G)
{
  int e = blockIdx.x * 256 + threadIdx.x;          // grid 80 -> 20480
  u64* pmax = (u64*)((char*)wsf + pmax_off);
  u32* gmax = (u32*)((char*)wsf + gmax_off);
  if (e < 16384){
    u64 m = 0ull;
    for (int s = 0; s < P; ++s){ u64 v = pmax[s*16384 + e]; if (v > m) m = v; }
    float val = __uint_as_float((u32)(m >> 32));
    u32 idx = 0xFFFFFFFFu - (u32)(m & 0xFFFFFFFFull);
    wsf[GFO + e] = val;
    out[4096 + e] = (float)idx;                    // max_indices, fp32
  } else if (e < 20480){
    int e2 = e - 16384;
    u32 mg = 0u;
    for (int s = 0; s < G; ++s){ u32 v = gmax[s*4096 + e2]; if (v > mg) mg = v; }
    wsf[GCFO + e2] = __uint_as_float(mg);
  }
}

// ---------------- small MLPs: one wave per dot product ----------------
__global__ __launch_bounds__(256) void k_mlp1(float* __restrict__ wsf,
    const float* __restrict__ wg0, const float* __restrict__ bg0,
    const float* __restrict__ wgr0, const float* __restrict__ bgr0)
{
  int wid = (blockIdx.x * 256 + threadIdx.x) >> 6;   // grid 2176 -> 8704 waves
  int lane = threadIdx.x & 63;
  if (wid < 8192){                                   // of1 = relu(gf @ wg0^T + bg0)
    int b = wid >> 9, o = wid & 511;
    const float* gf = wsf + GFO + b*1024;
    float s = 0.f;
    #pragma unroll
    for (int i = 0; i < 16; ++i){ int k = lane + (i << 6); s = fmaf(gf[k], wg0[o*1024 + k], s); }
    for (int off = 32; off; off >>= 1) s += __shfl_down(s, off);
    if (lane == 0) wsf[OF1O + b*512 + o] = fmaxf(s + bg0[o], 0.f);
  } else if (wid < 8704){                            // gr1 = relu(gcf @ wgr0^T + bgr0)
    int o = wid - 8192;
    const float* gcf = wsf + GCFO;
    float s = 0.f;
    #pragma unroll 8
    for (int i = 0; i < 64; ++i){ int k = lane + (i << 6); s = fmaf(gcf[k], wgr0[o*4096 + k], s); }
    for (int off = 32; off; off >>= 1) s += __shfl_down(s, off);
    if (lane == 0) wsf[GR1O + o] = fmaxf(s + bgr0[o], 0.f);
  }
}

__global__ __launch_bounds__(256) void k_mlp2(const float* __restrict__ wsf,
    const float* __restrict__ wg1, const float* __restrict__ bg1,
    const float* __restrict__ wgr1, const float* __restrict__ bgr1,
    float* __restrict__ out)
{
  int wid = (blockIdx.x * 256 + threadIdx.x) >> 6;   // grid 544 -> 2176 waves
  int lane = threadIdx.x & 63;
  if (wid < 2048){                                   // output_feature -> feature[:,128:256]
    int b = wid >> 7, o = wid & 127;
    const float* of1 = wsf + OF1O + b*512;
    float s = 0.f;
    #pragma unroll
    for (int i = 0; i < 8; ++i){ int k = lane + (i << 6); s = fmaf(of1[k], wg1[o*512 + k], s); }
    for (int off = 32; off; off >>= 1) s += __shfl_down(s, off);
    if (lane == 0) out[b*256 + 128 + o] = fmaxf(s + bg1[o], 0.f);
  } else if (wid < 2176){                            // group_output_feature -> feature[:,0:128]
    int o = wid - 2048;
    const float* gr1 = wsf + GR1O;
    float s = 0.f;
    #pragma unroll
    for (int i = 0; i < 8; ++i){ int k = lane + (i << 6); s = fmaf(gr1[k], wgr1[o*512 + k], s); }
    for (int off = 32; off; off >>= 1) s += __shfl_down(s, off);
    if (lane == 0){
      float r = fmaxf(s + bgr1[o], 0.f);
      for (int bb = 0; bb < 16; ++bb) out[bb*256 + o] = r;   // identical across batch
    }
  }
}

extern "C" void kernel_launch(void* const* d_in, const int* in_sizes, int n_in,
                              void* d_out, int out_size, void* d_ws, size_t ws_size,
                              hipStream_t stream)
{
  const float* pts  = (const float*)d_in[0];
  const float* wl0  = (const float*)d_in[1];  const float* bl0 = (const float*)d_in[2];
  const float* wl1  = (const float*)d_in[3];  const float* bl1 = (const float*)d_in[4];
  const float* wl2  = (const float*)d_in[5];  const float* bl2 = (const float*)d_in[6];
  const float* wl3  = (const float*)d_in[7];  const float* bl3 = (const float*)d_in[8];
  const float* wl4  = (const float*)d_in[9];  const float* bl4 = (const float*)d_in[10];
  const float* wg0  = (const float*)d_in[11]; const float* bg0 = (const float*)d_in[12];
  const float* wg1  = (const float*)d_in[13]; const float* bg1 = (const float*)d_in[14];
  const float* wgr0 = (const float*)d_in[15]; const float* bgr0 = (const float*)d_in[16];
  const float* wgr1 = (const float*)d_in[17]; const float* bgr1 = (const float*)d_in[18];
  float* wsf = (float*)d_ws;
  float* out = (float*)d_out;

  // ws-adaptive: pmax P slots (128 KB), gmax G slots (16 KB),
  // Wb fp16x2 (512 KB) + Wb1/2/3 (16+16+32 KB)
  int P, G;
  if      (ws_size >= 2400000) { P = 8; G = 16; }   // 2.09 MB
  else if (ws_size >= 1700000) { P = 4; G = 8;  }   // 1.43 MB
  else if (ws_size >= 1360000) { P = 2; G = 4;  }   // 1.11 MB
  else                         { P = 1; G = 2;  }   // 0.94 MB
  u32 pmax_off = FIXED_BYTES;
  u32 gmax_off = pmax_off + (u32)P * 131072u;
  u32 wb_off   = gmax_off + (u32)G * 16384u;
  u32 wb1_off  = wb_off + 524288u;
  u32 wb2_off  = wb1_off + 16384u;
  u32 wb3_off  = wb2_off + 16384u;

  k_prep<<<dim3(1024), dim3(256), 0, stream>>>(wl0, wl1, wl2, wl3, wl4,
      bl0, bl1, bl2, bl3, bl4, wsf, pmax_off, gmax_off, wb_off, P, G);
  k_main<<<dim3(4096), dim3(256), 0, stream>>>(pts, wsf,
      (const u16b*)((char*)d_ws + wb_off),  (const u16b*)((char*)d_ws + wb1_off),
      (const u16b*)((char*)d_ws + wb2_off), (const u16b*)((char*)d_ws + wb3_off),
      (u64*)((char*)d_ws + pmax_off), (u32*)((char*)d_ws + gmax_off), P-1, G-1);
  k_reduce<<<dim3(80), dim3(256), 0, stream>>>(wsf, out, pmax_off, gmax_off, P, G);
  k_mlp1<<<dim3(2176), dim3(256), 0, stream>>>(wsf, wg0, bg0, wgr0, bgr0);
  k_mlp2<<<dim3(544), dim3(256), 0, stream>>>(wsf, wg1, bg1, wgr1, bgr1, out);
}

// Round 5
// 374.297 us; speedup vs baseline: 1.4823x; 1.4823x over previous
//
#include <hip/hip_runtime.h>
#include <stdint.h>

typedef unsigned int u32;
typedef unsigned long long u64;
typedef unsigned short u16b;
typedef __attribute__((ext_vector_type(8))) _Float16 half8;  // 8 fp16 = 4 VGPR (MFMA A/B frag)
typedef __attribute__((ext_vector_type(4))) float v4f;       // MFMA C/D frag

constexpr int NP = 16384;   // points per batch
// ---- fixed float-region offsets (in floats) ----
constexpr int W0T = 0;        // [8][64] fp32 (L0 stays VALU)
constexpr int B0F = 16896, B1F = 16960, B2F = 17024, B3F = 17088, B4F = 17216;
constexpr int GFO = 18240;    // gf  [16][1024]
constexpr int GCFO = 34624;   // gcf [4][1024]
constexpr int OF1O = 38720;   // of1 [16][512]
constexpr int GR1O = 46912;   // gr1 [512]
constexpr int FIXED_FLOATS = 47424;
constexpr u32 FIXED_BYTES = FIXED_FLOATS * 4;   // 189696 B

struct __align__(16) f4 { float x, y, z, w; };

// fp16 split-2 with scaled low part: x ~= h + 2^-11 * l, both fp16-normal.
__device__ __forceinline__ void split2(float x, u16b& h, u16b& l){
  _Float16 hh = (_Float16)x;                 // v_cvt_f16_f32 (RNE)
  float r = (x - (float)hh) * 2048.f;        // exact subtract, exact *2^11
  _Float16 ll = (_Float16)r;
  union { _Float16 f; u16b u; } a, b; a.f = hh; b.f = ll;
  h = a.u; l = b.u;
}

__device__ __forceinline__ void fma4(f4& c, float s, const f4& a){
  c.x = fmaf(s, a.x, c.x); c.y = fmaf(s, a.y, c.y);
  c.z = fmaf(s, a.z, c.z); c.w = fmaf(s, a.w, c.w);
}

// row swizzle: phys row = S ^ ((S>>3)&7). Bijective (triangular). Makes the
// MFMA-D-layout b16 frag stores conflict-free and keeps reads bijective.
__device__ __forceinline__ int swz(int S){ return S ^ ((S >> 3) & 7); }

// ---------------- prep ----------------
// Wb  (L4, fp16x2): [s][kc4][nt][lane][j]   u16 addr = s*131072 + kc*32768 + nt*512 + L*8 + j
// Wb1 (L1, fp16x2): [s][kc2][cb4][lane][j]  u16 addr = s*4096 + kc*2048 + cb*512 + slot*8 + j
// Wb2 (L2): same as Wb1.  Wb3 (L3): [s][kc2][cb8][lane][j]  plane 8192 u16.
__global__ __launch_bounds__(256) void k_prep(
    const float* __restrict__ wl0, const float* __restrict__ wl1, const float* __restrict__ wl2,
    const float* __restrict__ wl3, const float* __restrict__ wl4,
    const float* __restrict__ bl0, const float* __restrict__ bl1, const float* __restrict__ bl2,
    const float* __restrict__ bl3, const float* __restrict__ bl4,
    float* __restrict__ wsf, u32 pmax_off, u32 gmax_off, u32 wb_off, int P, int G)
{
  int tid = blockIdx.x * 256 + threadIdx.x;            // grid 1024 -> 262144 threads
  u64* pmax = (u64*)((char*)wsf + pmax_off);
  u32* gmax = (u32*)((char*)wsf + gmax_off);
  if (tid < P * 16384) pmax[tid] = 0ull;
  if (tid < G * 4096)  gmax[tid] = 0u;
  if (tid < 131072){                                   // W5 split -> Wb (2 planes)
    int ch = tid >> 7, k = tid & 127;
    float x = wl4[tid];
    u16b h, l; split2(x, h, l);
    int kc = k >> 5, q = (k >> 3) & 3, j = k & 7, nt = ch >> 4;
    u32 base = (u32)kc*32768u + (u32)nt*512u + (u32)(((ch & 15) | (q << 4)) * 8 + j);
    u16b* wb = (u16b*)((char*)wsf + wb_off);
    wb[base] = h; wb[131072u + base] = l;
  }
  if (tid < 4096){                                     // W1 split -> Wb1
    int o = tid >> 6, c = tid & 63;
    float x = wl1[tid];
    u16b h, l; split2(x, h, l);
    u32 a = (u32)((c>>5)*2048 + (o>>4)*512 + (((o&15) | (((c>>3)&3)<<4)) << 3) + (c&7));
    u16b* p = (u16b*)((char*)wsf + wb_off + 524288u);
    p[a] = h; p[4096u + a] = l;
  }
  if (tid < 4096){                                     // W2 split -> Wb2
    int o = tid >> 6, c = tid & 63;
    float x = wl2[tid];
    u16b h, l; split2(x, h, l);
    u32 a = (u32)((c>>5)*2048 + (o>>4)*512 + (((o&15) | (((c>>3)&3)<<4)) << 3) + (c&7));
    u16b* p = (u16b*)((char*)wsf + wb_off + 524288u + 16384u);
    p[a] = h; p[4096u + a] = l;
  }
  if (tid < 8192){                                     // W3 split -> Wb3
    int o = tid >> 6, c = tid & 63;                    // o 0..127
    float x = wl3[tid];
    u16b h, l; split2(x, h, l);
    u32 a = (u32)((c>>5)*4096 + (o>>4)*512 + (((o&15) | (((c>>3)&3)<<4)) << 3) + (c&7));
    u16b* p = (u16b*)((char*)wsf + wb_off + 524288u + 32768u);
    p[a] = h; p[8192u + a] = l;
  }
  if (tid < 512){ int k = tid >> 6, o = tid & 63;
    wsf[W0T + tid] = (k < 7) ? wl0[o*7 + k] : 0.f; }
  if (tid < 64)   wsf[B0F + tid] = bl0[tid];
  if (tid < 64)   wsf[B1F + tid] = bl1[tid];
  if (tid < 64)   wsf[B2F + tid] = bl2[tid];
  if (tid < 128)  wsf[B3F + tid] = bl3[tid];
  if (tid < 1024) wsf[B4F + tid] = bl4[tid];
}

// 4pt x 4ch micro-tile for L0 (K=7; acts from LDS, weights L2-resident)
template<int K, int OSTR>
__device__ __forceinline__ void gemm4(const float* Ain, const float* __restrict__ Wt,
                                      int pt4, int o4, f4 (&acc)[4])
{
  #pragma unroll
  for (int oi = 0; oi < 4; ++oi) acc[oi] = f4{0.f,0.f,0.f,0.f};
  #pragma unroll
  for (int k = 0; k < K; ++k){
    f4 a = *(const f4*)(Ain + k*64 + pt4);
    f4 w = *(const f4*)(Wt + k*OSTR + o4);
    fma4(acc[0], w.x, a); fma4(acc[1], w.y, a);
    fma4(acc[2], w.z, a); fma4(acc[3], w.w, a);
  }
}

// one 64->64 MFMA layer (fp16 split-2, 3-term). Fin/Fout: frag buffers
// [plane][frag = m*2+kc][phys row 64][j 8], plane stride 4096 u16.
__device__ __forceinline__ void layer64(const u16b* Fin, u16b* Fout,
    const u16b* __restrict__ wbL, const float* __restrict__ wsf, int bofs,
    int w, int L, int sigL)
{
  v4f D0[4], D1[4];
  #pragma unroll
  for (int m = 0; m < 4; ++m){ D0[m] = (v4f)(0.f); D1[m] = (v4f)(0.f); }
  #pragma unroll
  for (int kc = 0; kc < 2; ++kc){
    const u16b* wp = wbL + (u32)(kc*2048 + w*512 + L*8);
    half8 b0 = *(const half8*)(wp);
    half8 b1 = *(const half8*)(wp + 4096);
    #pragma unroll
    for (int m = 0; m < 4; ++m){
      const u16b* fa = Fin + (u32)((m*2 + kc)*512 + sigL*8);
      half8 a0 = *(const half8*)(fa);
      half8 a1 = *(const half8*)(fa + 4096);
      D0[m] = __builtin_amdgcn_mfma_f32_16x16x32_f16(a0, b0, D0[m], 0, 0, 0);
      D1[m] = __builtin_amdgcn_mfma_f32_16x16x32_f16(a1, b0, D1[m], 0, 0, 0);
      D1[m] = __builtin_amdgcn_mfma_f32_16x16x32_f16(a0, b1, D1[m], 0, 0, 0);
    }
  }
  // epilogue: combine, bias, relu, split2, frag-store (D layout: ch=L&15 fixed, 4 pts/lane)
  int ch = (w << 4) + (L & 15);
  float bias = wsf[bofs + ch];
  int kcO = ch >> 5, q = (ch >> 3) & 3, j = ch & 7;
  int rowb = (L >> 4) << 2;                  // pt&15 base
  #pragma unroll
  for (int m = 0; m < 4; ++m){
    #pragma unroll
    for (int r = 0; r < 4; ++r){
      float v = fmaxf(fmaf(D1[m][r], 0x1p-11f, D0[m][r]) + bias, 0.f);
      u16b h, l; split2(v, h, l);
      int Sp = swz((rowb + r) | (q << 4));
      u32 a = (u32)((m*2 + kcO)*512 + Sp*8 + j);
      Fout[a] = h; Fout[4096u + a] = l;
    }
  }
}

// ---------------- fused local MLP: L0 fp32 VALU, L1-L4 fp16-split2 MFMA ----------------
// LDS 49152 B (2 blocks/CU, same residency as 32KB per r3's null result), u16 view LB:
//   FA = LB u16[0..8192)   (planes 0 / 4096)  | FB = LB u16[8192..16384)
//   F4 = LB u16[0..16384)  (planes 0 / 8192)  -- whole first 32 KB, after L3 drains
//   gmL = bytes [32768..49152): per-block group-max table [ch 1024][g 4] u32.
//     Group maxes go through ds_max (LDS atomic pipe) instead of 12 VALU
//     selects/slot -- the single largest VALU block in the kernel (r4 analysis).
//   A0F raw pts + gmS live in the gmL region during L0 (dead by the time gmL
//     is initialized between s5 and s6).
// __launch_bounds__(256,2): r4 showed (256,3) lifts occupancy to 3 blocks/CU but
// forces register spills (FETCH 6->14MB, WRITE 98->180MB) and regresses 402->488us.
__global__ __launch_bounds__(256, 2) void k_main(const float* __restrict__ pts,
    const float* __restrict__ wsf,
    const u16b* __restrict__ wb,  const u16b* __restrict__ wb1,
    const u16b* __restrict__ wb2, const u16b* __restrict__ wb3,
    u64* __restrict__ pmax, u32* __restrict__ gmax,
    int pmask, int gmask)
{
  __shared__ __align__(16) float sB[12288];    // 49152 B
  u16b* LB = (u16b*)sB;
  float* A0F = sB + 8192;                      // bytes 32768..34560 (gmL region, dead later)
  u32* gmL = (u32*)(sB + 8192);                // [ch][g] 1024*4 u32 = 16 KB
  const int t = threadIdx.x;
  const int b = blockIdx.x >> 8;
  const int tile = blockIdx.x & 255;
  const int n0 = tile * 64;
  const int w = t >> 6;            // wave id 0..3
  const int L = t & 63;
  const int sigL = swz(L);
  const int qb = (L >> 4) << 2;    // my D-row quad base

  u64* gmS = (u64*)(sB + 8640);                // after A0F, same scratch region
  if (t < 4) gmS[t] = 0ull;
  for (int e = t; e < 7*64; e += 256)
    A0F[e] = pts[(b*7 + (e >> 6))*NP + n0 + (e & 63)];
  __syncthreads();   // s1

  // per-point group id (argmax ch 3..6, first occurrence) -> 64-bit masks
  if (t < 64){
    float v = A0F[3*64 + t]; int gi = 0;
    float u1 = A0F[4*64 + t]; if (u1 > v){ v = u1; gi = 1; }
    float u2 = A0F[5*64 + t]; if (u2 > v){ v = u2; gi = 2; }
    float u3 = A0F[6*64 + t]; if (u3 > v){ v = u3; gi = 3; }
    atomicOr(&gmS[gi], 1ull << t);
  }

  // ---- L0 (VALU fp32) -> FA frag store (FA disjoint from A0F/gmS) ----
  const int pt4 = (t & 15) << 2, o4 = (t >> 4) << 2;
  f4 acc4[4];
  gemm4<7,64>(A0F, wsf + W0T, pt4, o4, acc4);
  {
    const int kc0 = o4 >> 5, q0 = (o4 >> 3) & 3, j0 = o4 & 7;
    #pragma unroll
    for (int jj = 0; jj < 4; ++jj){
      int pt = pt4 + jj; int m = pt >> 4;
      int Sp = swz((pt & 15) | (q0 << 4));
      u16b hh[4], ll[4];
      #pragma unroll
      for (int oi = 0; oi < 4; ++oi){
        float v = fmaxf(((const float*)&acc4[oi])[jj] + wsf[B0F + o4 + oi], 0.f);
        split2(v, hh[oi], ll[oi]);
      }
      u32 a = (u32)((m*2 + kc0)*512 + Sp*8 + j0);
      uint2 ph, pl;
      ph.x = (u32)hh[0] | ((u32)hh[1] << 16); ph.y = (u32)hh[2] | ((u32)hh[3] << 16);
      pl.x = (u32)ll[0] | ((u32)ll[1] << 16); pl.y = (u32)ll[2] | ((u32)ll[3] << 16);
      *(uint2*)(LB + a) = ph; *(uint2*)(LB + 4096u + a) = pl;
    }
  }
  __syncthreads();   // s2 (FA ready + masks done)

  // ggpack: 2-bit group id for each of my 16 D-slots (i = m*4+r -> pt = m*16+qb+r)
  u32 g1lo = (u32)gmS[1], g1hi = (u32)(gmS[1] >> 32);
  u32 g2lo = (u32)gmS[2], g2hi = (u32)(gmS[2] >> 32);
  u32 g3lo = (u32)gmS[3], g3hi = (u32)(gmS[3] >> 32);
  u32 ggpack = 0;
  #pragma unroll
  for (int i = 0; i < 16; ++i){
    int m = i >> 2, r = i & 3;
    int sh = ((m & 1) << 4) + qb + r;          // pt&31
    u32 b1 = ((m < 2 ? g1lo : g1hi) >> sh) & 1u;
    u32 b2 = ((m < 2 ? g2lo : g2hi) >> sh) & 1u;
    u32 b3 = ((m < 2 ? g3lo : g3hi) >> sh) & 1u;
    u32 g = b1 + (b2 << 1) + (b3 << 1) + b3;   // 0..3, one-hot source
    ggpack |= g << (2*i);
  }

  layer64(LB, LB + 8192, wb1, wsf, B1F, w, L, sigL);   // L1: FA -> FB
  __syncthreads();   // s3
  layer64(LB + 8192, LB, wb2, wsf, B2F, w, L, sigL);   // L2: FB -> FA
  __syncthreads();   // s4

  // ---- L3 (64->128): FA -> regs; wave w owns ch-blocks 2w, 2w+1, processed
  // SEQUENTIALLY with immediate fp32 fold -> peak accumulators 48 ----
  v4f Ef[2][4];
  #pragma unroll
  for (int c = 0; c < 2; ++c){
    v4f D0[4], D1[4];
    #pragma unroll
    for (int m = 0; m < 4; ++m){ D0[m] = (v4f)(0.f); D1[m] = (v4f)(0.f); }
    #pragma unroll
    for (int kc = 0; kc < 2; ++kc){
      const u16b* wp = wb3 + (u32)(kc*4096 + (w*2 + c)*512 + L*8);
      half8 b0 = *(const half8*)(wp);
      half8 b1 = *(const half8*)(wp + 8192);
      #pragma unroll
      for (int m = 0; m < 4; ++m){
        const u16b* fa = LB + (u32)((m*2 + kc)*512 + sigL*8);
        half8 a0 = *(const half8*)(fa);
        half8 a1 = *(const half8*)(fa + 4096);
        D0[m] = __builtin_amdgcn_mfma_f32_16x16x32_f16(a0, b0, D0[m], 0, 0, 0);
        D1[m] = __builtin_amdgcn_mfma_f32_16x16x32_f16(a1, b0, D1[m], 0, 0, 0);
        D1[m] = __builtin_amdgcn_mfma_f32_16x16x32_f16(a0, b1, D1[m], 0, 0, 0);
      }
    }
    #pragma unroll
    for (int m = 0; m < 4; ++m)
      #pragma unroll
      for (int r = 0; r < 4; ++r)
        Ef[c][m][r] = fmaf(D1[m][r], 0x1p-11f, D0[m][r]);
  }
  __syncthreads();   // s5 (all FA reads complete; F4 may overwrite FA+FB; A0F dead)

  // store F4 (planes 0 / 8192), frag = m*4 + (cb>>1); init gmL in parallel
  for (int e = t; e < 4096; e += 256) gmL[e] = 0u;
  #pragma unroll
  for (int c = 0; c < 2; ++c){
    int cb = w*2 + c;
    int ch = (cb << 4) + (L & 15);
    float bias = wsf[B3F + ch];
    int kc4 = cb >> 1, q = (ch >> 3) & 3, j = ch & 7;
    #pragma unroll
    for (int m = 0; m < 4; ++m){
      #pragma unroll
      for (int r = 0; r < 4; ++r){
        float v = fmaxf(Ef[c][m][r] + bias, 0.f);
        u16b h, l; split2(v, h, l);
        int Sp = swz((qb + r) | (q << 4));
        u32 a = (u32)((m*4 + kc4)*512 + Sp*8 + j);
        LB[a] = h; LB[8192u + a] = l;
      }
    }
  }
  __syncthreads();   // s6 (F4 + gmL ready)

  u64* pslot = pmax + (size_t)(tile & pmask)*(16*1024) + b*1024;
  u32* gslot = gmax + (size_t)(tile & gmask)*4096;
  const char* wbc = (const char*)wb;
  const u32 bvo = (u32)L * 16u;

  // ---- L4: 16 N-tiles/wave; 3-term fp16-split2 MFMA; B-frags software-pipelined.
  // Group maxes: one ds_max per slot into gmL[ch][g] (LDS pipe, ~2-way bank
  // conflict worst case) instead of 12 VALU select/max ops per slot. ----
  half8 bh, bl;
  {
    u32 bofs = ((u32)(w << 4)) * 1024u + bvo;        // (nt = w*16, kc = 0)
    bh = *(const half8*)(wbc +           bofs);
    bl = *(const half8*)(wbc + 262144u + bofs);
  }
  for (int nti = 0; nti < 16; ++nti){
    const int nt = (w << 4) + nti;
    const u32 chL = (u32)(nt << 4) + (u32)(L & 15);
    float bias = wsf[B4F + chL];                     // issue early
    v4f D0[4], D1[4];
    #pragma unroll
    for (int m = 0; m < 4; ++m){ D0[m] = (v4f)(0.f); D1[m] = (v4f)(0.f); }
    #pragma unroll
    for (int kc = 0; kc < 4; ++kc){
      half8 cb0 = bh, cb1 = bl;
      {
        int knext = (kc == 3) ? 0 : kc + 1;
        int ntn   = (kc == 3) ? nt + 1 : nt;
        u32 bofs = (u32)knext*65536u + (u32)ntn*1024u + bvo;
        bh = *(const half8*)(wbc +           bofs);
        bl = *(const half8*)(wbc + 262144u + bofs);
      }
      #pragma unroll
      for (int m = 0; m < 4; ++m){
        const u16b* fb = LB + (u32)((m*4 + kc)*512 + sigL*8);
        half8 a0 = *(const half8*)(fb);
        half8 a1 = *(const half8*)(fb + 8192);
        D0[m] = __builtin_amdgcn_mfma_f32_16x16x32_f16(a0, cb0, D0[m], 0, 0, 0);
        D1[m] = __builtin_amdgcn_mfma_f32_16x16x32_f16(a1, cb0, D1[m], 0, 0, 0);
        D1[m] = __builtin_amdgcn_mfma_f32_16x16x32_f16(a0, cb1, D1[m], 0, 0, 0);
      }
    }
    // epilogue: combine splits, bias+relu, per-lane argmax, group ds_max
    u32* gmRow = gmL + (chL << 2);
    float mx = 0.f; int mi = 0;
    #pragma unroll
    for (int m = 0; m < 4; ++m){
      #pragma unroll
      for (int r = 0; r < 4; ++r){
        int i = m*4 + r;
        float v = fmaxf(fmaf(D1[m][r], 0x1p-11f, D0[m][r]) + bias, 0.f);
        int pidx = n0 + m*16 + qb + r;
        if (i == 0){ mx = v; mi = pidx; }
        else if (v > mx){ mx = v; mi = pidx; }
        u32 g = (ggpack >> (2*i)) & 3u;
        atomicMax(gmRow + g, __float_as_uint(v));
      }
    }
    #pragma unroll
    for (int s = 16; s <= 32; s <<= 1){
      float m2 = __shfl_xor(mx, s);
      int  i2  = __shfl_xor(mi, s);
      if (m2 > mx || (m2 == mx && i2 < mi)){ mx = m2; mi = i2; }
    }
    if (L < 16){
      int ch = (nt << 4) + L;
      u64 pk = ((u64)__float_as_uint(mx) << 32) | (u64)(0xFFFFFFFFu - (u32)mi);
      atomicMax(pslot + ch, pk);
    }
  }

  // drain per-block group maxes to global (batched; replaces per-nti atomics)
  __syncthreads();   // s7 (all ds_max done)
  for (int e = t; e < 4096; e += 256){
    u32 val = gmL[e];                              // e = ch*4 + g
    if (val) atomicMax(gslot + ((e & 3) << 10) + (e >> 2), val);
  }
}

// ---------------- fold slots; emit max_indices (fp32) + gf + gcf ----------------
__global__ __launch_bounds__(256) void k_reduce(float* __restrict__ wsf, float* __restrict__ out,
                                                u32 pmax_off, u32 gmax_off, int P, int G)
{
  int e = blockIdx.x * 256 + threadIdx.x;          // grid 80 -> 20480
  u64* pmax = (u64*)((char*)wsf + pmax_off);
  u32* gmax = (u32*)((char*)wsf + gmax_off);
  if (e < 16384){
    u64 m = 0ull;
    for (int s = 0; s < P; ++s){ u64 v = pmax[s*16384 + e]; if (v > m) m = v; }
    float val = __uint_as_float((u32)(m >> 32));
    u32 idx = 0xFFFFFFFFu - (u32)(m & 0xFFFFFFFFull);
    wsf[GFO + e] = val;
    out[4096 + e] = (float)idx;                    // max_indices, fp32
  } else if (e < 20480){
    int e2 = e - 16384;
    u32 mg = 0u;
    for (int s = 0; s < G; ++s){ u32 v = gmax[s*4096 + e2]; if (v > mg) mg = v; }
    wsf[GCFO + e2] = __uint_as_float(mg);
  }
}

// ---------------- small MLPs: one wave per dot product ----------------
__global__ __launch_bounds__(256) void k_mlp1(float* __restrict__ wsf,
    const float* __restrict__ wg0, const float* __restrict__ bg0,
    const float* __restrict__ wgr0, const float* __restrict__ bgr0)
{
  int wid = (blockIdx.x * 256 + threadIdx.x) >> 6;   // grid 2176 -> 8704 waves
  int lane = threadIdx.x & 63;
  if (wid < 8192){                                   // of1 = relu(gf @ wg0^T + bg0)
    int b = wid >> 9, o = wid & 511;
    const float* gf = wsf + GFO + b*1024;
    float s = 0.f;
    #pragma unroll
    for (int i = 0; i < 16; ++i){ int k = lane + (i << 6); s = fmaf(gf[k], wg0[o*1024 + k], s); }
    for (int off = 32; off; off >>= 1) s += __shfl_down(s, off);
    if (lane == 0) wsf[OF1O + b*512 + o] = fmaxf(s + bg0[o], 0.f);
  } else if (wid < 8704){                            // gr1 = relu(gcf @ wgr0^T + bgr0)
    int o = wid - 8192;
    const float* gcf = wsf + GCFO;
    float s = 0.f;
    #pragma unroll 8
    for (int i = 0; i < 64; ++i){ int k = lane + (i << 6); s = fmaf(gcf[k], wgr0[o*4096 + k], s); }
    for (int off = 32; off; off >>= 1) s += __shfl_down(s, off);
    if (lane == 0) wsf[GR1O + o] = fmaxf(s + bgr0[o], 0.f);
  }
}

__global__ __launch_bounds__(256) void k_mlp2(const float* __restrict__ wsf,
    const float* __restrict__ wg1, const float* __restrict__ bg1,
    const float* __restrict__ wgr1, const float* __restrict__ bgr1,
    float* __restrict__ out)
{
  int wid = (blockIdx.x * 256 + threadIdx.x) >> 6;   // grid 544 -> 2176 waves
  int lane = threadIdx.x & 63;
  if (wid < 2048){                                   // output_feature -> feature[:,128:256]
    int b = wid >> 7, o = wid & 127;
    const float* of1 = wsf + OF1O + b*512;
    float s = 0.f;
    #pragma unroll
    for (int i = 0; i < 8; ++i){ int k = lane + (i << 6); s = fmaf(of1[k], wg1[o*512 + k], s); }
    for (int off = 32; off; off >>= 1) s += __shfl_down(s, off);
    if (lane == 0) out[b*256 + 128 + o] = fmaxf(s + bg1[o], 0.f);
  } else if (wid < 2176){                            // group_output_feature -> feature[:,0:128]
    int o = wid - 2048;
    const float* gr1 = wsf + GR1O;
    float s = 0.f;
    #pragma unroll
    for (int i = 0; i < 8; ++i){ int k = lane + (i << 6); s = fmaf(gr1[k], wgr1[o*512 + k], s); }
    for (int off = 32; off; off >>= 1) s += __shfl_down(s, off);
    if (lane == 0){
      float r = fmaxf(s + bgr1[o], 0.f);
      for (int bb = 0; bb < 16; ++bb) out[bb*256 + o] = r;   // identical across batch
    }
  }
}

extern "C" void kernel_launch(void* const* d_in, const int* in_sizes, int n_in,
                              void* d_out, int out_size, void* d_ws, size_t ws_size,
                              hipStream_t stream)
{
  const float* pts  = (const float*)d_in[0];
  const float* wl0  = (const float*)d_in[1];  const float* bl0 = (const float*)d_in[2];
  const float* wl1  = (const float*)d_in[3];  const float* bl1 = (const float*)d_in[4];
  const float* wl2  = (const float*)d_in[5];  const float* bl2 = (const float*)d_in[6];
  const float* wl3  = (const float*)d_in[7];  const float* bl3 = (const float*)d_in[8];
  const float* wl4  = (const float*)d_in[9];  const float* bl4 = (const float*)d_in[10];
  const float* wg0  = (const float*)d_in[11]; const float* bg0 = (const float*)d_in[12];
  const float* wg1  = (const float*)d_in[13]; const float* bg1 = (const float*)d_in[14];
  const float* wgr0 = (const float*)d_in[15]; const float* bgr0 = (const float*)d_in[16];
  const float* wgr1 = (const float*)d_in[17]; const float* bgr1 = (const float*)d_in[18];
  float* wsf = (float*)d_ws;
  float* out = (float*)d_out;

  // ws-adaptive: pmax P slots (128 KB), gmax G slots (16 KB),
  // Wb fp16x2 (512 KB) + Wb1/2/3 (16+16+32 KB)
  int P, G;
  if      (ws_size >= 2400000) { P = 8; G = 16; }   // 2.09 MB
  else if (ws_size >= 1700000) { P = 4; G = 8;  }   // 1.43 MB
  else if (ws_size >= 1360000) { P = 2; G = 4;  }   // 1.11 MB
  else                         { P = 1; G = 2;  }   // 0.94 MB
  u32 pmax_off = FIXED_BYTES;
  u32 gmax_off = pmax_off + (u32)P * 131072u;
  u32 wb_off   = gmax_off + (u32)G * 16384u;
  u32 wb1_off  = wb_off + 524288u;
  u32 wb2_off  = wb1_off + 16384u;
  u32 wb3_off  = wb2_off + 16384u;

  k_prep<<<dim3(1024), dim3(256), 0, stream>>>(wl0, wl1, wl2, wl3, wl4,
      bl0, bl1, bl2, bl3, bl4, wsf, pmax_off, gmax_off, wb_off, P, G);
  k_main<<<dim3(4096), dim3(256), 0, stream>>>(pts, wsf,
      (const u16b*)((char*)d_ws + wb_off),  (const u16b*)((char*)d_ws + wb1_off),
      (const u16b*)((char*)d_ws + wb2_off), (const u16b*)((char*)d_ws + wb3_off),
      (u64*)((char*)d_ws + pmax_off), (u32*)((char*)d_ws + gmax_off), P-1, G-1);
  k_reduce<<<dim3(80), dim3(256), 0, stream>>>(wsf, out, pmax_off, gmax_off, P, G);
  k_mlp1<<<dim3(2176), dim3(256), 0, stream>>>(wsf, wg0, bg0, wgr0, bgr0);
  k_mlp2<<<dim3(544), dim3(256), 0, stream>>>(wsf, wg1, bg1, wgr1, bgr1, out);
}

// Round 6
// 371.268 us; speedup vs baseline: 1.4944x; 1.0082x over previous
//
#include <hip/hip_runtime.h>
#include <stdint.h>

typedef unsigned int u32;
typedef unsigned long long u64;
typedef unsigned short u16b;
typedef __attribute__((ext_vector_type(8))) _Float16 half8;  // 8 fp16 = 4 VGPR (MFMA A/B frag)
typedef __attribute__((ext_vector_type(4))) float v4f;       // MFMA C/D frag

constexpr int NP = 16384;   // points per batch
// ---- fixed float-region offsets (in floats) ----
constexpr int W0T = 0;        // [8][64] fp32 (L0 stays VALU)
constexpr int B0F = 16896, B1F = 16960, B2F = 17024, B3F = 17088, B4F = 17216;
constexpr int GFO = 18240;    // gf  [16][1024]
constexpr int GCFO = 34624;   // gcf [4][1024]
constexpr int OF1O = 38720;   // of1 [16][512]
constexpr int GR1O = 46912;   // gr1 [512]
constexpr int FIXED_FLOATS = 47424;
constexpr u32 FIXED_BYTES = FIXED_FLOATS * 4;   // 189696 B

struct __align__(16) f4 { float x, y, z, w; };

// fp16 split-2 with scaled low part: x ~= h + 2^-11 * l, both fp16-normal.
__device__ __forceinline__ void split2(float x, u16b& h, u16b& l){
  _Float16 hh = (_Float16)x;                 // v_cvt_f16_f32 (RNE)
  float r = (x - (float)hh) * 2048.f;        // exact subtract, exact *2^11
  _Float16 ll = (_Float16)r;
  union { _Float16 f; u16b u; } a, b; a.f = hh; b.f = ll;
  h = a.u; l = b.u;
}

__device__ __forceinline__ void fma4(f4& c, float s, const f4& a){
  c.x = fmaf(s, a.x, c.x); c.y = fmaf(s, a.y, c.y);
  c.z = fmaf(s, a.z, c.z); c.w = fmaf(s, a.w, c.w);
}

// row swizzle: phys row = S ^ ((S>>3)&7). Bijective (triangular). Makes the
// MFMA-D-layout b16 frag stores conflict-free and keeps reads bijective.
__device__ __forceinline__ int swz(int S){ return S ^ ((S >> 3) & 7); }

// ---------------- prep ----------------
// Wb  (L4, fp16x2): [s][kc4][nt][lane][j]   u16 addr = s*131072 + kc*32768 + nt*512 + L*8 + j
// Wb1 (L1, fp16x2): [s][kc2][cb4][lane][j]  u16 addr = s*4096 + kc*2048 + cb*512 + slot*8 + j
// Wb2 (L2): same as Wb1.  Wb3 (L3): [s][kc2][cb8][lane][j]  plane 8192 u16.
__global__ __launch_bounds__(256) void k_prep(
    const float* __restrict__ wl0, const float* __restrict__ wl1, const float* __restrict__ wl2,
    const float* __restrict__ wl3, const float* __restrict__ wl4,
    const float* __restrict__ bl0, const float* __restrict__ bl1, const float* __restrict__ bl2,
    const float* __restrict__ bl3, const float* __restrict__ bl4,
    float* __restrict__ wsf, u32 pmax_off, u32 gmax_off, u32 wb_off, int P, int G)
{
  int tid = blockIdx.x * 256 + threadIdx.x;            // grid 1024 -> 262144 threads
  u64* pmax = (u64*)((char*)wsf + pmax_off);
  u32* gmax = (u32*)((char*)wsf + gmax_off);
  if (tid < P * 16384) pmax[tid] = 0ull;
  if (tid < G * 4096)  gmax[tid] = 0u;
  if (tid < 131072){                                   // W5 split -> Wb (2 planes)
    int ch = tid >> 7, k = tid & 127;
    float x = wl4[tid];
    u16b h, l; split2(x, h, l);
    int kc = k >> 5, q = (k >> 3) & 3, j = k & 7, nt = ch >> 4;
    u32 base = (u32)kc*32768u + (u32)nt*512u + (u32)(((ch & 15) | (q << 4)) * 8 + j);
    u16b* wb = (u16b*)((char*)wsf + wb_off);
    wb[base] = h; wb[131072u + base] = l;
  }
  if (tid < 4096){                                     // W1 split -> Wb1
    int o = tid >> 6, c = tid & 63;
    float x = wl1[tid];
    u16b h, l; split2(x, h, l);
    u32 a = (u32)((c>>5)*2048 + (o>>4)*512 + (((o&15) | (((c>>3)&3)<<4)) << 3) + (c&7));
    u16b* p = (u16b*)((char*)wsf + wb_off + 524288u);
    p[a] = h; p[4096u + a] = l;
  }
  if (tid < 4096){                                     // W2 split -> Wb2
    int o = tid >> 6, c = tid & 63;
    float x = wl2[tid];
    u16b h, l; split2(x, h, l);
    u32 a = (u32)((c>>5)*2048 + (o>>4)*512 + (((o&15) | (((c>>3)&3)<<4)) << 3) + (c&7));
    u16b* p = (u16b*)((char*)wsf + wb_off + 524288u + 16384u);
    p[a] = h; p[4096u + a] = l;
  }
  if (tid < 8192){                                     // W3 split -> Wb3
    int o = tid >> 6, c = tid & 63;                    // o 0..127
    float x = wl3[tid];
    u16b h, l; split2(x, h, l);
    u32 a = (u32)((c>>5)*4096 + (o>>4)*512 + (((o&15) | (((c>>3)&3)<<4)) << 3) + (c&7));
    u16b* p = (u16b*)((char*)wsf + wb_off + 524288u + 32768u);
    p[a] = h; p[8192u + a] = l;
  }
  if (tid < 512){ int k = tid >> 6, o = tid & 63;
    wsf[W0T + tid] = (k < 7) ? wl0[o*7 + k] : 0.f; }
  if (tid < 64)   wsf[B0F + tid] = bl0[tid];
  if (tid < 64)   wsf[B1F + tid] = bl1[tid];
  if (tid < 64)   wsf[B2F + tid] = bl2[tid];
  if (tid < 128)  wsf[B3F + tid] = bl3[tid];
  if (tid < 1024) wsf[B4F + tid] = bl4[tid];
}

// 4pt x 4ch micro-tile for L0 (K=7; acts from LDS, weights L2-resident)
template<int K, int OSTR>
__device__ __forceinline__ void gemm4(const float* Ain, const float* __restrict__ Wt,
                                      int pt4, int o4, f4 (&acc)[4])
{
  #pragma unroll
  for (int oi = 0; oi < 4; ++oi) acc[oi] = f4{0.f,0.f,0.f,0.f};
  #pragma unroll
  for (int k = 0; k < K; ++k){
    f4 a = *(const f4*)(Ain + k*64 + pt4);
    f4 w = *(const f4*)(Wt + k*OSTR + o4);
    fma4(acc[0], w.x, a); fma4(acc[1], w.y, a);
    fma4(acc[2], w.z, a); fma4(acc[3], w.w, a);
  }
}

// one 64->64 MFMA layer (fp16 split-2, 3-term). Fin/Fout: frag buffers
// [plane][frag = m*2+kc][phys row 64][j 8], plane stride 4096 u16.
__device__ __forceinline__ void layer64(const u16b* Fin, u16b* Fout,
    const u16b* __restrict__ wbL, const float* __restrict__ wsf, int bofs,
    int w, int L, int sigL)
{
  v4f D0[4], D1[4];
  #pragma unroll
  for (int m = 0; m < 4; ++m){ D0[m] = (v4f)(0.f); D1[m] = (v4f)(0.f); }
  #pragma unroll
  for (int kc = 0; kc < 2; ++kc){
    const u16b* wp = wbL + (u32)(kc*2048 + w*512 + L*8);
    half8 b0 = *(const half8*)(wp);
    half8 b1 = *(const half8*)(wp + 4096);
    #pragma unroll
    for (int m = 0; m < 4; ++m){
      const u16b* fa = Fin + (u32)((m*2 + kc)*512 + sigL*8);
      half8 a0 = *(const half8*)(fa);
      half8 a1 = *(const half8*)(fa + 4096);
      D0[m] = __builtin_amdgcn_mfma_f32_16x16x32_f16(a0, b0, D0[m], 0, 0, 0);
      D1[m] = __builtin_amdgcn_mfma_f32_16x16x32_f16(a1, b0, D1[m], 0, 0, 0);
      D1[m] = __builtin_amdgcn_mfma_f32_16x16x32_f16(a0, b1, D1[m], 0, 0, 0);
    }
  }
  // epilogue: combine, bias, relu, split2, frag-store (D layout: ch=L&15 fixed, 4 pts/lane)
  int ch = (w << 4) + (L & 15);
  float bias = wsf[bofs + ch];
  int kcO = ch >> 5, q = (ch >> 3) & 3, j = ch & 7;
  int rowb = (L >> 4) << 2;                  // pt&15 base
  #pragma unroll
  for (int m = 0; m < 4; ++m){
    #pragma unroll
    for (int r = 0; r < 4; ++r){
      float v = fmaxf(fmaf(D1[m][r], 0x1p-11f, D0[m][r]) + bias, 0.f);
      u16b h, l; split2(v, h, l);
      int Sp = swz((rowb + r) | (q << 4));
      u32 a = (u32)((m*2 + kcO)*512 + Sp*8 + j);
      Fout[a] = h; Fout[4096u + a] = l;
    }
  }
}

// ---------------- fused local MLP: L0 fp32 VALU, L1-L4 fp16-split2 MFMA ----------------
// LDS 49152 B (3 blocks/CU measured r5), u16 view LB:
//   FA = LB u16[0..8192)   (planes 0 / 4096)  | FB = LB u16[8192..16384)
//   F4 = LB u16[0..16384)  (planes 0 / 8192)  -- whole first 32 KB, after L3 drains
//   gmL = bytes [32768..49152): per-block group-max table [ch 1024][g 4] u32 (ds_max pipe).
//   A0F raw pts + gmS live in the gmL region during L0 (dead before gmL init).
// __launch_bounds__(256,2): (256,3) forces spills (r4). At VGPR<=128 HW gives
// 3 blocks/CU on its own (r5: occupancy 31%).
// L4 epilogue VALU trim (r6): bias pre-loaded into D0's MFMA C-operand (ch is
// slot-invariant), and ds_max byte-offsets voff[16] precomputed once (ggpack and
// lane ch-offset are nti-invariant; only nt*256 varies).
__global__ __launch_bounds__(256, 2) void k_main(const float* __restrict__ pts,
    const float* __restrict__ wsf,
    const u16b* __restrict__ wb,  const u16b* __restrict__ wb1,
    const u16b* __restrict__ wb2, const u16b* __restrict__ wb3,
    u64* __restrict__ pmax, u32* __restrict__ gmax,
    int pmask, int gmask)
{
  __shared__ __align__(16) float sB[12288];    // 49152 B
  u16b* LB = (u16b*)sB;
  float* A0F = sB + 8192;                      // bytes 32768..34560 (gmL region, dead later)
  u32* gmL = (u32*)(sB + 8192);                // [ch][g] 1024*4 u32 = 16 KB
  const int t = threadIdx.x;
  const int b = blockIdx.x >> 8;
  const int tile = blockIdx.x & 255;
  const int n0 = tile * 64;
  const int w = t >> 6;            // wave id 0..3
  const int L = t & 63;
  const int sigL = swz(L);
  const int qb = (L >> 4) << 2;    // my D-row quad base

  u64* gmS = (u64*)(sB + 8640);                // after A0F, same scratch region
  if (t < 4) gmS[t] = 0ull;
  for (int e = t; e < 7*64; e += 256)
    A0F[e] = pts[(b*7 + (e >> 6))*NP + n0 + (e & 63)];
  __syncthreads();   // s1

  // per-point group id (argmax ch 3..6, first occurrence) -> 64-bit masks
  if (t < 64){
    float v = A0F[3*64 + t]; int gi = 0;
    float u1 = A0F[4*64 + t]; if (u1 > v){ v = u1; gi = 1; }
    float u2 = A0F[5*64 + t]; if (u2 > v){ v = u2; gi = 2; }
    float u3 = A0F[6*64 + t]; if (u3 > v){ v = u3; gi = 3; }
    atomicOr(&gmS[gi], 1ull << t);
  }

  // ---- L0 (VALU fp32) -> FA frag store (FA disjoint from A0F/gmS) ----
  const int pt4 = (t & 15) << 2, o4 = (t >> 4) << 2;
  f4 acc4[4];
  gemm4<7,64>(A0F, wsf + W0T, pt4, o4, acc4);
  {
    const int kc0 = o4 >> 5, q0 = (o4 >> 3) & 3, j0 = o4 & 7;
    #pragma unroll
    for (int jj = 0; jj < 4; ++jj){
      int pt = pt4 + jj; int m = pt >> 4;
      int Sp = swz((pt & 15) | (q0 << 4));
      u16b hh[4], ll[4];
      #pragma unroll
      for (int oi = 0; oi < 4; ++oi){
        float v = fmaxf(((const float*)&acc4[oi])[jj] + wsf[B0F + o4 + oi], 0.f);
        split2(v, hh[oi], ll[oi]);
      }
      u32 a = (u32)((m*2 + kc0)*512 + Sp*8 + j0);
      uint2 ph, pl;
      ph.x = (u32)hh[0] | ((u32)hh[1] << 16); ph.y = (u32)hh[2] | ((u32)hh[3] << 16);
      pl.x = (u32)ll[0] | ((u32)ll[1] << 16); pl.y = (u32)ll[2] | ((u32)ll[3] << 16);
      *(uint2*)(LB + a) = ph; *(uint2*)(LB + 4096u + a) = pl;
    }
  }
  __syncthreads();   // s2 (FA ready + masks done)

  // ggpack: 2-bit group id for each of my 16 D-slots (i = m*4+r -> pt = m*16+qb+r)
  u32 g1lo = (u32)gmS[1], g1hi = (u32)(gmS[1] >> 32);
  u32 g2lo = (u32)gmS[2], g2hi = (u32)(gmS[2] >> 32);
  u32 g3lo = (u32)gmS[3], g3hi = (u32)(gmS[3] >> 32);
  u32 ggpack = 0;
  #pragma unroll
  for (int i = 0; i < 16; ++i){
    int m = i >> 2, r = i & 3;
    int sh = ((m & 1) << 4) + qb + r;          // pt&31
    u32 b1 = ((m < 2 ? g1lo : g1hi) >> sh) & 1u;
    u32 b2 = ((m < 2 ? g2lo : g2hi) >> sh) & 1u;
    u32 b3 = ((m < 2 ? g3lo : g3hi) >> sh) & 1u;
    u32 g = b1 + (b2 << 1) + (b3 << 1) + b3;   // 0..3, one-hot source
    ggpack |= g << (2*i);
  }

  layer64(LB, LB + 8192, wb1, wsf, B1F, w, L, sigL);   // L1: FA -> FB
  __syncthreads();   // s3
  layer64(LB + 8192, LB, wb2, wsf, B2F, w, L, sigL);   // L2: FB -> FA
  __syncthreads();   // s4

  // ---- L3 (64->128): FA -> regs; wave w owns ch-blocks 2w, 2w+1, processed
  // SEQUENTIALLY with immediate fp32 fold -> peak accumulators 48 ----
  v4f Ef[2][4];
  #pragma unroll
  for (int c = 0; c < 2; ++c){
    v4f D0[4], D1[4];
    #pragma unroll
    for (int m = 0; m < 4; ++m){ D0[m] = (v4f)(0.f); D1[m] = (v4f)(0.f); }
    #pragma unroll
    for (int kc = 0; kc < 2; ++kc){
      const u16b* wp = wb3 + (u32)(kc*4096 + (w*2 + c)*512 + L*8);
      half8 b0 = *(const half8*)(wp);
      half8 b1 = *(const half8*)(wp + 8192);
      #pragma unroll
      for (int m = 0; m < 4; ++m){
        const u16b* fa = LB + (u32)((m*2 + kc)*512 + sigL*8);
        half8 a0 = *(const half8*)(fa);
        half8 a1 = *(const half8*)(fa + 4096);
        D0[m] = __builtin_amdgcn_mfma_f32_16x16x32_f16(a0, b0, D0[m], 0, 0, 0);
        D1[m] = __builtin_amdgcn_mfma_f32_16x16x32_f16(a1, b0, D1[m], 0, 0, 0);
        D1[m] = __builtin_amdgcn_mfma_f32_16x16x32_f16(a0, b1, D1[m], 0, 0, 0);
      }
    }
    #pragma unroll
    for (int m = 0; m < 4; ++m)
      #pragma unroll
      for (int r = 0; r < 4; ++r)
        Ef[c][m][r] = fmaf(D1[m][r], 0x1p-11f, D0[m][r]);
  }
  __syncthreads();   // s5 (all FA reads complete; F4 may overwrite FA+FB; A0F dead)

  // store F4 (planes 0 / 8192), frag = m*4 + (cb>>1); init gmL in parallel
  for (int e = t; e < 4096; e += 256) gmL[e] = 0u;
  #pragma unroll
  for (int c = 0; c < 2; ++c){
    int cb = w*2 + c;
    int ch = (cb << 4) + (L & 15);
    float bias = wsf[B3F + ch];
    int kc4 = cb >> 1, q = (ch >> 3) & 3, j = ch & 7;
    #pragma unroll
    for (int m = 0; m < 4; ++m){
      #pragma unroll
      for (int r = 0; r < 4; ++r){
        float v = fmaxf(Ef[c][m][r] + bias, 0.f);
        u16b h, l; split2(v, h, l);
        int Sp = swz((qb + r) | (q << 4));
        u32 a = (u32)((m*4 + kc4)*512 + Sp*8 + j);
        LB[a] = h; LB[8192u + a] = l;
      }
    }
  }
  __syncthreads();   // s6 (F4 + gmL ready)

  u64* pslot = pmax + (size_t)(tile & pmask)*(16*1024) + b*1024;
  u32* gslot = gmax + (size_t)(tile & gmask)*4096;
  const char* wbc = (const char*)wb;
  const u32 bvo = (u32)L * 16u;

  // nti-invariant ds_max byte offsets within a gmL nt-row (ggpack dies here)
  u32 voff[16];
  #pragma unroll
  for (int i = 0; i < 16; ++i)
    voff[i] = (u32)((L & 15) << 4) + (((ggpack >> (2*i)) & 3u) << 2);

  // ---- L4: 16 N-tiles/wave; 3-term fp16-split2 MFMA; B-frags software-pipelined.
  // bias rides in D0's C-in; group maxes via ds_max at precomputed offsets. ----
  half8 bh, bl;
  {
    u32 bofs = ((u32)(w << 4)) * 1024u + bvo;        // (nt = w*16, kc = 0)
    bh = *(const half8*)(wbc +           bofs);
    bl = *(const half8*)(wbc + 262144u + bofs);
  }
  for (int nti = 0; nti < 16; ++nti){
    const int nt = (w << 4) + nti;
    const u32 chL = (u32)(nt << 4) + (u32)(L & 15);
    float bias = wsf[B4F + chL];                     // issue early
    v4f D0[4], D1[4];
    #pragma unroll
    for (int m = 0; m < 4; ++m){
      D0[m][0] = bias; D0[m][1] = bias; D0[m][2] = bias; D0[m][3] = bias;
      D1[m] = (v4f)(0.f);
    }
    #pragma unroll
    for (int kc = 0; kc < 4; ++kc){
      half8 cb0 = bh, cb1 = bl;
      {
        int knext = (kc == 3) ? 0 : kc + 1;
        int ntn   = (kc == 3) ? nt + 1 : nt;
        u32 bofs = (u32)knext*65536u + (u32)ntn*1024u + bvo;
        bh = *(const half8*)(wbc +           bofs);
        bl = *(const half8*)(wbc + 262144u + bofs);
      }
      #pragma unroll
      for (int m = 0; m < 4; ++m){
        const u16b* fb = LB + (u32)((m*4 + kc)*512 + sigL*8);
        half8 a0 = *(const half8*)(fb);
        half8 a1 = *(const half8*)(fb + 8192);
        D0[m] = __builtin_amdgcn_mfma_f32_16x16x32_f16(a0, cb0, D0[m], 0, 0, 0);
        D1[m] = __builtin_amdgcn_mfma_f32_16x16x32_f16(a1, cb0, D1[m], 0, 0, 0);
        D1[m] = __builtin_amdgcn_mfma_f32_16x16x32_f16(a0, cb1, D1[m], 0, 0, 0);
      }
    }
    // epilogue: combine splits (bias already in D0), relu, argmax, group ds_max
    char* gmNT = (char*)gmL + (nt << 8);
    float mx = 0.f; int mi = 0;
    #pragma unroll
    for (int m = 0; m < 4; ++m){
      #pragma unroll
      for (int r = 0; r < 4; ++r){
        int i = m*4 + r;
        float v = fmaxf(fmaf(D1[m][r], 0x1p-11f, D0[m][r]), 0.f);
        int pidx = n0 + m*16 + qb + r;
        if (i == 0){ mx = v; mi = pidx; }
        else if (v > mx){ mx = v; mi = pidx; }
        atomicMax((u32*)(gmNT + voff[i]), __float_as_uint(v));
      }
    }
    #pragma unroll
    for (int s = 16; s <= 32; s <<= 1){
      float m2 = __shfl_xor(mx, s);
      int  i2  = __shfl_xor(mi, s);
      if (m2 > mx || (m2 == mx && i2 < mi)){ mx = m2; mi = i2; }
    }
    if (L < 16){
      int ch = (nt << 4) + L;
      u64 pk = ((u64)__float_as_uint(mx) << 32) | (u64)(0xFFFFFFFFu - (u32)mi);
      atomicMax(pslot + ch, pk);
    }
  }

  // drain per-block group maxes to global (batched; replaces per-nti atomics)
  __syncthreads();   // s7 (all ds_max done)
  for (int e = t; e < 4096; e += 256){
    u32 val = gmL[e];                              // e = ch*4 + g
    if (val) atomicMax(gslot + ((e & 3) << 10) + (e >> 2), val);
  }
}

// ---------------- fold slots; emit max_indices (fp32) + gf + gcf ----------------
__global__ __launch_bounds__(256) void k_reduce(float* __restrict__ wsf, float* __restrict__ out,
                                                u32 pmax_off, u32 gmax_off, int P, int G)
{
  int e = blockIdx.x * 256 + threadIdx.x;          // grid 80 -> 20480
  u64* pmax = (u64*)((char*)wsf + pmax_off);
  u32* gmax = (u32*)((char*)wsf + gmax_off);
  if (e < 16384){
    u64 m = 0ull;
    for (int s = 0; s < P; ++s){ u64 v = pmax[s*16384 + e]; if (v > m) m = v; }
    float val = __uint_as_float((u32)(m >> 32));
    u32 idx = 0xFFFFFFFFu - (u32)(m & 0xFFFFFFFFull);
    wsf[GFO + e] = val;
    out[4096 + e] = (float)idx;                    // max_indices, fp32
  } else if (e < 20480){
    int e2 = e - 16384;
    u32 mg = 0u;
    for (int s = 0; s < G; ++s){ u32 v = gmax[s*4096 + e2]; if (v > mg) mg = v; }
    wsf[GCFO + e2] = __uint_as_float(mg);
  }
}

// ---------------- small MLPs: one wave per dot product ----------------
__global__ __launch_bounds__(256) void k_mlp1(float* __restrict__ wsf,
    const float* __restrict__ wg0, const float* __restrict__ bg0,
    const float* __restrict__ wgr0, const float* __restrict__ bgr0)
{
  int wid = (blockIdx.x * 256 + threadIdx.x) >> 6;   // grid 2176 -> 8704 waves
  int lane = threadIdx.x & 63;
  if (wid < 8192){                                   // of1 = relu(gf @ wg0^T + bg0)
    int b = wid >> 9, o = wid & 511;
    const float* gf = wsf + GFO + b*1024;
    float s = 0.f;
    #pragma unroll
    for (int i = 0; i < 16; ++i){ int k = lane + (i << 6); s = fmaf(gf[k], wg0[o*1024 + k], s); }
    for (int off = 32; off; off >>= 1) s += __shfl_down(s, off);
    if (lane == 0) wsf[OF1O + b*512 + o] = fmaxf(s + bg0[o], 0.f);
  } else if (wid < 8704){                            // gr1 = relu(gcf @ wgr0^T + bgr0)
    int o = wid - 8192;
    const float* gcf = wsf + GCFO;
    float s = 0.f;
    #pragma unroll 8
    for (int i = 0; i < 64; ++i){ int k = lane + (i << 6); s = fmaf(gcf[k], wgr0[o*4096 + k], s); }
    for (int off = 32; off; off >>= 1) s += __shfl_down(s, off);
    if (lane == 0) wsf[GR1O + o] = fmaxf(s + bgr0[o], 0.f);
  }
}

__global__ __launch_bounds__(256) void k_mlp2(const float* __restrict__ wsf,
    const float* __restrict__ wg1, const float* __restrict__ bg1,
    const float* __restrict__ wgr1, const float* __restrict__ bgr1,
    float* __restrict__ out)
{
  int wid = (blockIdx.x * 256 + threadIdx.x) >> 6;   // grid 544 -> 2176 waves
  int lane = threadIdx.x & 63;
  if (wid < 2048){                                   // output_feature -> feature[:,128:256]
    int b = wid >> 7, o = wid & 127;
    const float* of1 = wsf + OF1O + b*512;
    float s = 0.f;
    #pragma unroll
    for (int i = 0; i < 8; ++i){ int k = lane + (i << 6); s = fmaf(of1[k], wg1[o*512 + k], s); }
    for (int off = 32; off; off >>= 1) s += __shfl_down(s, off);
    if (lane == 0) out[b*256 + 128 + o] = fmaxf(s + bg1[o], 0.f);
  } else if (wid < 2176){                            // group_output_feature -> feature[:,0:128]
    int o = wid - 2048;
    const float* gr1 = wsf + GR1O;
    float s = 0.f;
    #pragma unroll
    for (int i = 0; i < 8; ++i){ int k = lane + (i << 6); s = fmaf(gr1[k], wgr1[o*512 + k], s); }
    for (int off = 32; off; off >>= 1) s += __shfl_down(s, off);
    if (lane == 0){
      float r = fmaxf(s + bgr1[o], 0.f);
      for (int bb = 0; bb < 16; ++bb) out[bb*256 + o] = r;   // identical across batch
    }
  }
}

extern "C" void kernel_launch(void* const* d_in, const int* in_sizes, int n_in,
                              void* d_out, int out_size, void* d_ws, size_t ws_size,
                              hipStream_t stream)
{
  const float* pts  = (const float*)d_in[0];
  const float* wl0  = (const float*)d_in[1];  const float* bl0 = (const float*)d_in[2];
  const float* wl1  = (const float*)d_in[3];  const float* bl1 = (const float*)d_in[4];
  const float* wl2  = (const float*)d_in[5];  const float* bl2 = (const float*)d_in[6];
  const float* wl3  = (const float*)d_in[7];  const float* bl3 = (const float*)d_in[8];
  const float* wl4  = (const float*)d_in[9];  const float* bl4 = (const float*)d_in[10];
  const float* wg0  = (const float*)d_in[11]; const float* bg0 = (const float*)d_in[12];
  const float* wg1  = (const float*)d_in[13]; const float* bg1 = (const float*)d_in[14];
  const float* wgr0 = (const float*)d_in[15]; const float* bgr0 = (const float*)d_in[16];
  const float* wgr1 = (const float*)d_in[17]; const float* bgr1 = (const float*)d_in[18];
  float* wsf = (float*)d_ws;
  float* out = (float*)d_out;

  // ws-adaptive: pmax P slots (128 KB), gmax G slots (16 KB),
  // Wb fp16x2 (512 KB) + Wb1/2/3 (16+16+32 KB)
  int P, G;
  if      (ws_size >= 2400000) { P = 8; G = 16; }   // 2.09 MB
  else if (ws_size >= 1700000) { P = 4; G = 8;  }   // 1.43 MB
  else if (ws_size >= 1360000) { P = 2; G = 4;  }   // 1.11 MB
  else                         { P = 1; G = 2;  }   // 0.94 MB
  u32 pmax_off = FIXED_BYTES;
  u32 gmax_off = pmax_off + (u32)P * 131072u;
  u32 wb_off   = gmax_off + (u32)G * 16384u;
  u32 wb1_off  = wb_off + 524288u;
  u32 wb2_off  = wb1_off + 16384u;
  u32 wb3_off  = wb2_off + 16384u;

  k_prep<<<dim3(1024), dim3(256), 0, stream>>>(wl0, wl1, wl2, wl3, wl4,
      bl0, bl1, bl2, bl3, bl4, wsf, pmax_off, gmax_off, wb_off, P, G);
  k_main<<<dim3(4096), dim3(256), 0, stream>>>(pts, wsf,
      (const u16b*)((char*)d_ws + wb_off),  (const u16b*)((char*)d_ws + wb1_off),
      (const u16b*)((char*)d_ws + wb2_off), (const u16b*)((char*)d_ws + wb3_off),
      (u64*)((char*)d_ws + pmax_off), (u32*)((char*)d_ws + gmax_off), P-1, G-1);
  k_reduce<<<dim3(80), dim3(256), 0, stream>>>(wsf, out, pmax_off, gmax_off, P, G);
  k_mlp1<<<dim3(2176), dim3(256), 0, stream>>>(wsf, wg0, bg0, wgr0, bgr0);
  k_mlp2<<<dim3(544), dim3(256), 0, stream>>>(wsf, wg1, bg1, wgr1, bgr1, out);
}

// Round 7
// 346.646 us; speedup vs baseline: 1.6005x; 1.0710x over previous
//
#include <hip/hip_runtime.h>
#include <stdint.h>

typedef unsigned int u32;
typedef unsigned long long u64;
typedef unsigned short u16b;
typedef __attribute__((ext_vector_type(8))) _Float16 half8;  // 8 fp16 = 4 VGPR (MFMA A/B frag)
typedef __attribute__((ext_vector_type(4))) float v4f;       // MFMA C/D frag

constexpr int NP = 16384;   // points per batch
// ---- fixed float-region offsets (in floats) ----
constexpr int W0T = 0;        // [8][64] fp32 (L0 stays VALU)
constexpr int B0F = 16896, B1F = 16960, B2F = 17024, B3F = 17088, B4F = 17216;
constexpr int GFO = 18240;    // gf  [16][1024]
constexpr int GCFO = 34624;   // gcf [4][1024]
constexpr int OF1O = 38720;   // of1 [16][512]
constexpr int GR1O = 46912;   // gr1 [512]
constexpr int FIXED_FLOATS = 47424;
constexpr u32 FIXED_BYTES = FIXED_FLOATS * 4;   // 189696 B

struct __align__(16) f4 { float x, y, z, w; };

// fp16 split-2 with scaled low part: x ~= h + 2^-11 * l, both fp16-normal.
__device__ __forceinline__ void split2(float x, u16b& h, u16b& l){
  _Float16 hh = (_Float16)x;                 // v_cvt_f16_f32 (RNE)
  float r = (x - (float)hh) * 2048.f;        // exact subtract, exact *2^11
  _Float16 ll = (_Float16)r;
  union { _Float16 f; u16b u; } a, b; a.f = hh; b.f = ll;
  h = a.u; l = b.u;
}

__device__ __forceinline__ void fma4(f4& c, float s, const f4& a){
  c.x = fmaf(s, a.x, c.x); c.y = fmaf(s, a.y, c.y);
  c.z = fmaf(s, a.z, c.z); c.w = fmaf(s, a.w, c.w);
}

// row swizzle: phys row = S ^ ((S>>3)&7). Bijective (triangular). Makes the
// MFMA-D-layout b16 frag stores conflict-free and keeps reads bijective.
__device__ __forceinline__ int swz(int S){ return S ^ ((S >> 3) & 7); }

// ---------------- prep ----------------
// Wb  (L4, fp16x2): [s][kc4][nt][lane][j]   u16 addr = s*131072 + kc*32768 + nt*512 + L*8 + j
// Wb1 (L1, fp16x2): [s][kc2][cb4][lane][j]  u16 addr = s*4096 + kc*2048 + cb*512 + slot*8 + j
// Wb2 (L2): same as Wb1.  Wb3 (L3): [s][kc2][cb8][lane][j]  plane 8192 u16.
__global__ __launch_bounds__(256) void k_prep(
    const float* __restrict__ wl0, const float* __restrict__ wl1, const float* __restrict__ wl2,
    const float* __restrict__ wl3, const float* __restrict__ wl4,
    const float* __restrict__ bl0, const float* __restrict__ bl1, const float* __restrict__ bl2,
    const float* __restrict__ bl3, const float* __restrict__ bl4,
    float* __restrict__ wsf, u32 pmax_off, u32 gmax_off, u32 wb_off, int P, int G)
{
  int tid = blockIdx.x * 256 + threadIdx.x;            // grid 1024 -> 262144 threads
  u64* pmax = (u64*)((char*)wsf + pmax_off);
  u32* gmax = (u32*)((char*)wsf + gmax_off);
  if (tid < P * 16384) pmax[tid] = 0ull;
  if (tid < G * 4096)  gmax[tid] = 0u;
  if (tid < 131072){                                   // W5 split -> Wb (2 planes)
    int ch = tid >> 7, k = tid & 127;
    float x = wl4[tid];
    u16b h, l; split2(x, h, l);
    int kc = k >> 5, q = (k >> 3) & 3, j = k & 7, nt = ch >> 4;
    u32 base = (u32)kc*32768u + (u32)nt*512u + (u32)(((ch & 15) | (q << 4)) * 8 + j);
    u16b* wb = (u16b*)((char*)wsf + wb_off);
    wb[base] = h; wb[131072u + base] = l;
  }
  if (tid < 4096){                                     // W1 split -> Wb1
    int o = tid >> 6, c = tid & 63;
    float x = wl1[tid];
    u16b h, l; split2(x, h, l);
    u32 a = (u32)((c>>5)*2048 + (o>>4)*512 + (((o&15) | (((c>>3)&3)<<4)) << 3) + (c&7));
    u16b* p = (u16b*)((char*)wsf + wb_off + 524288u);
    p[a] = h; p[4096u + a] = l;
  }
  if (tid < 4096){                                     // W2 split -> Wb2
    int o = tid >> 6, c = tid & 63;
    float x = wl2[tid];
    u16b h, l; split2(x, h, l);
    u32 a = (u32)((c>>5)*2048 + (o>>4)*512 + (((o&15) | (((c>>3)&3)<<4)) << 3) + (c&7));
    u16b* p = (u16b*)((char*)wsf + wb_off + 524288u + 16384u);
    p[a] = h; p[4096u + a] = l;
  }
  if (tid < 8192){                                     // W3 split -> Wb3
    int o = tid >> 6, c = tid & 63;                    // o 0..127
    float x = wl3[tid];
    u16b h, l; split2(x, h, l);
    u32 a = (u32)((c>>5)*4096 + (o>>4)*512 + (((o&15) | (((c>>3)&3)<<4)) << 3) + (c&7));
    u16b* p = (u16b*)((char*)wsf + wb_off + 524288u + 32768u);
    p[a] = h; p[8192u + a] = l;
  }
  if (tid < 512){ int k = tid >> 6, o = tid & 63;
    wsf[W0T + tid] = (k < 7) ? wl0[o*7 + k] : 0.f; }
  if (tid < 64)   wsf[B0F + tid] = bl0[tid];
  if (tid < 64)   wsf[B1F + tid] = bl1[tid];
  if (tid < 64)   wsf[B2F + tid] = bl2[tid];
  if (tid < 128)  wsf[B3F + tid] = bl3[tid];
  if (tid < 1024) wsf[B4F + tid] = bl4[tid];
}

// 4pt x 4ch micro-tile for L0 (K=7; acts from LDS, weights L2-resident)
template<int K, int OSTR>
__device__ __forceinline__ void gemm4(const float* Ain, const float* __restrict__ Wt,
                                      int pt4, int o4, f4 (&acc)[4])
{
  #pragma unroll
  for (int oi = 0; oi < 4; ++oi) acc[oi] = f4{0.f,0.f,0.f,0.f};
  #pragma unroll
  for (int k = 0; k < K; ++k){
    f4 a = *(const f4*)(Ain + k*64 + pt4);
    f4 w = *(const f4*)(Wt + k*OSTR + o4);
    fma4(acc[0], w.x, a); fma4(acc[1], w.y, a);
    fma4(acc[2], w.z, a); fma4(acc[3], w.w, a);
  }
}

// one 64->64 MFMA layer (fp16 split-2, 3-term). Fin/Fout: frag buffers
// [plane][frag = m*2+kc][phys row 64][j 8], plane stride 4096 u16.
__device__ __forceinline__ void layer64(const u16b* Fin, u16b* Fout,
    const u16b* __restrict__ wbL, const float* __restrict__ wsf, int bofs,
    int w, int L, int sigL)
{
  v4f D0[4], D1[4];
  #pragma unroll
  for (int m = 0; m < 4; ++m){ D0[m] = (v4f)(0.f); D1[m] = (v4f)(0.f); }
  #pragma unroll
  for (int kc = 0; kc < 2; ++kc){
    const u16b* wp = wbL + (u32)(kc*2048 + w*512 + L*8);
    half8 b0 = *(const half8*)(wp);
    half8 b1 = *(const half8*)(wp + 4096);
    #pragma unroll
    for (int m = 0; m < 4; ++m){
      const u16b* fa = Fin + (u32)((m*2 + kc)*512 + sigL*8);
      half8 a0 = *(const half8*)(fa);
      half8 a1 = *(const half8*)(fa + 4096);
      D0[m] = __builtin_amdgcn_mfma_f32_16x16x32_f16(a0, b0, D0[m], 0, 0, 0);
      D1[m] = __builtin_amdgcn_mfma_f32_16x16x32_f16(a1, b0, D1[m], 0, 0, 0);
      D1[m] = __builtin_amdgcn_mfma_f32_16x16x32_f16(a0, b1, D1[m], 0, 0, 0);
    }
  }
  // epilogue: combine, bias, relu, split2, frag-store (D layout: ch=L&15 fixed, 4 pts/lane)
  int ch = (w << 4) + (L & 15);
  float bias = wsf[bofs + ch];
  int kcO = ch >> 5, q = (ch >> 3) & 3, j = ch & 7;
  int rowb = (L >> 4) << 2;                  // pt&15 base
  #pragma unroll
  for (int m = 0; m < 4; ++m){
    #pragma unroll
    for (int r = 0; r < 4; ++r){
      float v = fmaxf(fmaf(D1[m][r], 0x1p-11f, D0[m][r]) + bias, 0.f);
      u16b h, l; split2(v, h, l);
      int Sp = swz((rowb + r) | (q << 4));
      u32 a = (u32)((m*2 + kcO)*512 + Sp*8 + j);
      Fout[a] = h; Fout[4096u + a] = l;
    }
  }
}

// ---------------- fused local MLP: L0 fp32 VALU, L1-L4 fp16-split2 MFMA ----------------
// LDS 49152 B (3 blocks/CU measured r5), u16 view LB:
//   FA = LB u16[0..8192)   (planes 0 / 4096)  | FB = LB u16[8192..16384)
//   F4 = LB u16[0..16384)  (planes 0 / 8192)  -- whole first 32 KB, after L3 drains
//   gmL = bytes [32768..49152): per-block group-max table [ch 1024][g 4] u32 (ds_max pipe).
//   A0F raw pts + gmS live in the gmL region during L0 (dead before gmL init).
// L4 (r7): 2 nt-tiles per iteration -- A-fragments are nt-invariant, so pairing
// halves the F4 LDS re-read traffic (2MB -> 1MB/block; LDS pipe was ~57% of
// kernel cycles, the fattest consumer). Acc 2x(D0,D1)[4] = 64 VGPR; total ~140,
// no spill at (256,2); occupancy stays LDS-limited at 3 blocks/CU.
__global__ __launch_bounds__(256, 2) void k_main(const float* __restrict__ pts,
    const float* __restrict__ wsf,
    const u16b* __restrict__ wb,  const u16b* __restrict__ wb1,
    const u16b* __restrict__ wb2, const u16b* __restrict__ wb3,
    u64* __restrict__ pmax, u32* __restrict__ gmax,
    int pmask, int gmask)
{
  __shared__ __align__(16) float sB[12288];    // 49152 B
  u16b* LB = (u16b*)sB;
  float* A0F = sB + 8192;                      // bytes 32768..34560 (gmL region, dead later)
  u32* gmL = (u32*)(sB + 8192);                // [ch][g] 1024*4 u32 = 16 KB
  const int t = threadIdx.x;
  const int b = blockIdx.x >> 8;
  const int tile = blockIdx.x & 255;
  const int n0 = tile * 64;
  const int w = t >> 6;            // wave id 0..3
  const int L = t & 63;
  const int sigL = swz(L);
  const int qb = (L >> 4) << 2;    // my D-row quad base

  u64* gmS = (u64*)(sB + 8640);                // after A0F, same scratch region
  if (t < 4) gmS[t] = 0ull;
  for (int e = t; e < 7*64; e += 256)
    A0F[e] = pts[(b*7 + (e >> 6))*NP + n0 + (e & 63)];
  __syncthreads();   // s1

  // per-point group id (argmax ch 3..6, first occurrence) -> 64-bit masks
  if (t < 64){
    float v = A0F[3*64 + t]; int gi = 0;
    float u1 = A0F[4*64 + t]; if (u1 > v){ v = u1; gi = 1; }
    float u2 = A0F[5*64 + t]; if (u2 > v){ v = u2; gi = 2; }
    float u3 = A0F[6*64 + t]; if (u3 > v){ v = u3; gi = 3; }
    atomicOr(&gmS[gi], 1ull << t);
  }

  // ---- L0 (VALU fp32) -> FA frag store (FA disjoint from A0F/gmS) ----
  const int pt4 = (t & 15) << 2, o4 = (t >> 4) << 2;
  f4 acc4[4];
  gemm4<7,64>(A0F, wsf + W0T, pt4, o4, acc4);
  {
    const int kc0 = o4 >> 5, q0 = (o4 >> 3) & 3, j0 = o4 & 7;
    #pragma unroll
    for (int jj = 0; jj < 4; ++jj){
      int pt = pt4 + jj; int m = pt >> 4;
      int Sp = swz((pt & 15) | (q0 << 4));
      u16b hh[4], ll[4];
      #pragma unroll
      for (int oi = 0; oi < 4; ++oi){
        float v = fmaxf(((const float*)&acc4[oi])[jj] + wsf[B0F + o4 + oi], 0.f);
        split2(v, hh[oi], ll[oi]);
      }
      u32 a = (u32)((m*2 + kc0)*512 + Sp*8 + j0);
      uint2 ph, pl;
      ph.x = (u32)hh[0] | ((u32)hh[1] << 16); ph.y = (u32)hh[2] | ((u32)hh[3] << 16);
      pl.x = (u32)ll[0] | ((u32)ll[1] << 16); pl.y = (u32)ll[2] | ((u32)ll[3] << 16);
      *(uint2*)(LB + a) = ph; *(uint2*)(LB + 4096u + a) = pl;
    }
  }
  __syncthreads();   // s2 (FA ready + masks done)

  // ggpack: 2-bit group id for each of my 16 D-slots (i = m*4+r -> pt = m*16+qb+r)
  u32 g1lo = (u32)gmS[1], g1hi = (u32)(gmS[1] >> 32);
  u32 g2lo = (u32)gmS[2], g2hi = (u32)(gmS[2] >> 32);
  u32 g3lo = (u32)gmS[3], g3hi = (u32)(gmS[3] >> 32);
  u32 ggpack = 0;
  #pragma unroll
  for (int i = 0; i < 16; ++i){
    int m = i >> 2, r = i & 3;
    int sh = ((m & 1) << 4) + qb + r;          // pt&31
    u32 b1 = ((m < 2 ? g1lo : g1hi) >> sh) & 1u;
    u32 b2 = ((m < 2 ? g2lo : g2hi) >> sh) & 1u;
    u32 b3 = ((m < 2 ? g3lo : g3hi) >> sh) & 1u;
    u32 g = b1 + (b2 << 1) + (b3 << 1) + b3;   // 0..3, one-hot source
    ggpack |= g << (2*i);
  }

  layer64(LB, LB + 8192, wb1, wsf, B1F, w, L, sigL);   // L1: FA -> FB
  __syncthreads();   // s3
  layer64(LB + 8192, LB, wb2, wsf, B2F, w, L, sigL);   // L2: FB -> FA
  __syncthreads();   // s4

  // ---- L3 (64->128): FA -> regs; wave w owns ch-blocks 2w, 2w+1, processed
  // SEQUENTIALLY with immediate fp32 fold -> peak accumulators 48 ----
  v4f Ef[2][4];
  #pragma unroll
  for (int c = 0; c < 2; ++c){
    v4f D0[4], D1[4];
    #pragma unroll
    for (int m = 0; m < 4; ++m){ D0[m] = (v4f)(0.f); D1[m] = (v4f)(0.f); }
    #pragma unroll
    for (int kc = 0; kc < 2; ++kc){
      const u16b* wp = wb3 + (u32)(kc*4096 + (w*2 + c)*512 + L*8);
      half8 b0 = *(const half8*)(wp);
      half8 b1 = *(const half8*)(wp + 8192);
      #pragma unroll
      for (int m = 0; m < 4; ++m){
        const u16b* fa = LB + (u32)((m*2 + kc)*512 + sigL*8);
        half8 a0 = *(const half8*)(fa);
        half8 a1 = *(const half8*)(fa + 4096);
        D0[m] = __builtin_amdgcn_mfma_f32_16x16x32_f16(a0, b0, D0[m], 0, 0, 0);
        D1[m] = __builtin_amdgcn_mfma_f32_16x16x32_f16(a1, b0, D1[m], 0, 0, 0);
        D1[m] = __builtin_amdgcn_mfma_f32_16x16x32_f16(a0, b1, D1[m], 0, 0, 0);
      }
    }
    #pragma unroll
    for (int m = 0; m < 4; ++m)
      #pragma unroll
      for (int r = 0; r < 4; ++r)
        Ef[c][m][r] = fmaf(D1[m][r], 0x1p-11f, D0[m][r]);
  }
  __syncthreads();   // s5 (all FA reads complete; F4 may overwrite FA+FB; A0F dead)

  // store F4 (planes 0 / 8192), frag = m*4 + (cb>>1); init gmL in parallel
  for (int e = t; e < 4096; e += 256) gmL[e] = 0u;
  #pragma unroll
  for (int c = 0; c < 2; ++c){
    int cb = w*2 + c;
    int ch = (cb << 4) + (L & 15);
    float bias = wsf[B3F + ch];
    int kc4 = cb >> 1, q = (ch >> 3) & 3, j = ch & 7;
    #pragma unroll
    for (int m = 0; m < 4; ++m){
      #pragma unroll
      for (int r = 0; r < 4; ++r){
        float v = fmaxf(Ef[c][m][r] + bias, 0.f);
        u16b h, l; split2(v, h, l);
        int Sp = swz((qb + r) | (q << 4));
        u32 a = (u32)((m*4 + kc4)*512 + Sp*8 + j);
        LB[a] = h; LB[8192u + a] = l;
      }
    }
  }
  __syncthreads();   // s6 (F4 + gmL ready)

  u64* pslot = pmax + (size_t)(tile & pmask)*(16*1024) + b*1024;
  u32* gslot = gmax + (size_t)(tile & gmask)*4096;
  const char* wbc = (const char*)wb;
  const u32 bvo = (u32)L * 16u;

  // nti-invariant ds_max byte offsets within a gmL nt-row (ggpack dies here)
  u32 voff[16];
  #pragma unroll
  for (int i = 0; i < 16; ++i)
    voff[i] = (u32)((L & 15) << 4) + (((ggpack >> (2*i)) & 3u) << 2);

  // ---- L4: 8 iterations x 2 nt-tiles; 3-term fp16-split2 MFMA; B prefetched.
  // Each A-frag LDS read feeds both nt's MFMAs (halves F4 re-read traffic). ----
  half8 bh0, bl0, bh1, bl1;
  {
    u32 base0 = ((u32)(w << 4)) * 1024u + bvo;       // (nt = w*16, kc = 0)
    bh0 = *(const half8*)(wbc +           base0);
    bl0 = *(const half8*)(wbc + 262144u + base0);
    bh1 = *(const half8*)(wbc +           base0 + 1024u);
    bl1 = *(const half8*)(wbc + 262144u + base0 + 1024u);
  }
  for (int nti = 0; nti < 8; ++nti){
    const int nt = (w << 4) + (nti << 1);            // pair nt, nt+1
    const u32 ch0 = (u32)(nt << 4) + (u32)(L & 15);
    float bias0 = wsf[B4F + ch0];                    // issue early
    float bias1 = wsf[B4F + ch0 + 16];
    v4f D0[2][4], D1[2][4];
    #pragma unroll
    for (int m = 0; m < 4; ++m){
      D0[0][m][0] = bias0; D0[0][m][1] = bias0; D0[0][m][2] = bias0; D0[0][m][3] = bias0;
      D0[1][m][0] = bias1; D0[1][m][1] = bias1; D0[1][m][2] = bias1; D0[1][m][3] = bias1;
      D1[0][m] = (v4f)(0.f); D1[1][m] = (v4f)(0.f);
    }
    #pragma unroll
    for (int kc = 0; kc < 4; ++kc){
      half8 c0h = bh0, c0l = bl0, c1h = bh1, c1l = bl1;
      {
        int knext = (kc == 3) ? 0 : kc + 1;
        int ntn   = (kc == 3) ? nt + 2 : nt;         // tail over-read stays in Wb
        u32 bofs = (u32)knext*65536u + (u32)ntn*1024u + bvo;
        bh0 = *(const half8*)(wbc +           bofs);
        bl0 = *(const half8*)(wbc + 262144u + bofs);
        bh1 = *(const half8*)(wbc +           bofs + 1024u);
        bl1 = *(const half8*)(wbc + 262144u + bofs + 1024u);
      }
      #pragma unroll
      for (int m = 0; m < 4; ++m){
        const u16b* fb = LB + (u32)((m*4 + kc)*512 + sigL*8);
        half8 a0 = *(const half8*)(fb);
        half8 a1 = *(const half8*)(fb + 8192);
        D0[0][m] = __builtin_amdgcn_mfma_f32_16x16x32_f16(a0, c0h, D0[0][m], 0, 0, 0);
        D0[1][m] = __builtin_amdgcn_mfma_f32_16x16x32_f16(a0, c1h, D0[1][m], 0, 0, 0);
        D1[0][m] = __builtin_amdgcn_mfma_f32_16x16x32_f16(a1, c0h, D1[0][m], 0, 0, 0);
        D1[1][m] = __builtin_amdgcn_mfma_f32_16x16x32_f16(a1, c1h, D1[1][m], 0, 0, 0);
        D1[0][m] = __builtin_amdgcn_mfma_f32_16x16x32_f16(a0, c0l, D1[0][m], 0, 0, 0);
        D1[1][m] = __builtin_amdgcn_mfma_f32_16x16x32_f16(a0, c1l, D1[1][m], 0, 0, 0);
      }
    }
    // epilogue x2: combine splits (bias in D0), relu, argmax, group ds_max
    #pragma unroll
    for (int p = 0; p < 2; ++p){
      char* gmNT = (char*)gmL + ((nt + p) << 8);
      float mx = 0.f; int mi = 0;
      #pragma unroll
      for (int m = 0; m < 4; ++m){
        #pragma unroll
        for (int r = 0; r < 4; ++r){
          int i = m*4 + r;
          float v = fmaxf(fmaf(D1[p][m][r], 0x1p-11f, D0[p][m][r]), 0.f);
          int pidx = n0 + m*16 + qb + r;
          if (i == 0){ mx = v; mi = pidx; }
          else if (v > mx){ mx = v; mi = pidx; }
          atomicMax((u32*)(gmNT + voff[i]), __float_as_uint(v));
        }
      }
      #pragma unroll
      for (int s = 16; s <= 32; s <<= 1){
        float m2 = __shfl_xor(mx, s);
        int  i2  = __shfl_xor(mi, s);
        if (m2 > mx || (m2 == mx && i2 < mi)){ mx = m2; mi = i2; }
      }
      if (L < 16){
        int ch = ((nt + p) << 4) + L;
        u64 pk = ((u64)__float_as_uint(mx) << 32) | (u64)(0xFFFFFFFFu - (u32)mi);
        atomicMax(pslot + ch, pk);
      }
    }
  }

  // drain per-block group maxes to global (batched; replaces per-nti atomics)
  __syncthreads();   // s7 (all ds_max done)
  for (int e = t; e < 4096; e += 256){
    u32 val = gmL[e];                              // e = ch*4 + g
    if (val) atomicMax(gslot + ((e & 3) << 10) + (e >> 2), val);
  }
}

// ---------------- fold slots; emit max_indices (fp32) + gf + gcf ----------------
__global__ __launch_bounds__(256) void k_reduce(float* __restrict__ wsf, float* __restrict__ out,
                                                u32 pmax_off, u32 gmax_off, int P, int G)
{
  int e = blockIdx.x * 256 + threadIdx.x;          // grid 80 -> 20480
  u64* pmax = (u64*)((char*)wsf + pmax_off);
  u32* gmax = (u32*)((char*)wsf + gmax_off);
  if (e < 16384){
    u64 m = 0ull;
    for (int s = 0; s < P; ++s){ u64 v = pmax[s*16384 + e]; if (v > m) m = v; }
    float val = __uint_as_float((u32)(m >> 32));
    u32 idx = 0xFFFFFFFFu - (u32)(m & 0xFFFFFFFFull);
    wsf[GFO + e] = val;
    out[4096 + e] = (float)idx;                    // max_indices, fp32
  } else if (e < 20480){
    int e2 = e - 16384;
    u32 mg = 0u;
    for (int s = 0; s < G; ++s){ u32 v = gmax[s*4096 + e2]; if (v > mg) mg = v; }
    wsf[GCFO + e2] = __uint_as_float(mg);
  }
}

// ---------------- small MLPs: one wave per dot product ----------------
__global__ __launch_bounds__(256) void k_mlp1(float* __restrict__ wsf,
    const float* __restrict__ wg0, const float* __restrict__ bg0,
    const float* __restrict__ wgr0, const float* __restrict__ bgr0)
{
  int wid = (blockIdx.x * 256 + threadIdx.x) >> 6;   // grid 2176 -> 8704 waves
  int lane = threadIdx.x & 63;
  if (wid < 8192){                                   // of1 = relu(gf @ wg0^T + bg0)
    int b = wid >> 9, o = wid & 511;
    const float* gf = wsf + GFO + b*1024;
    float s = 0.f;
    #pragma unroll
    for (int i = 0; i < 16; ++i){ int k = lane + (i << 6); s = fmaf(gf[k], wg0[o*1024 + k], s); }
    for (int off = 32; off; off >>= 1) s += __shfl_down(s, off);
    if (lane == 0) wsf[OF1O + b*512 + o] = fmaxf(s + bg0[o], 0.f);
  } else if (wid < 8704){                            // gr1 = relu(gcf @ wgr0^T + bgr0)
    int o = wid - 8192;
    const float* gcf = wsf + GCFO;
    float s = 0.f;
    #pragma unroll 8
    for (int i = 0; i < 64; ++i){ int k = lane + (i << 6); s = fmaf(gcf[k], wgr0[o*4096 + k], s); }
    for (int off = 32; off; off >>= 1) s += __shfl_down(s, off);
    if (lane == 0) wsf[GR1O + o] = fmaxf(s + bgr0[o], 0.f);
  }
}

__global__ __launch_bounds__(256) void k_mlp2(const float* __restrict__ wsf,
    const float* __restrict__ wg1, const float* __restrict__ bg1,
    const float* __restrict__ wgr1, const float* __restrict__ bgr1,
    float* __restrict__ out)
{
  int wid = (blockIdx.x * 256 + threadIdx.x) >> 6;   // grid 544 -> 2176 waves
  int lane = threadIdx.x & 63;
  if (wid < 2048){                                   // output_feature -> feature[:,128:256]
    int b = wid >> 7, o = wid & 127;
    const float* of1 = wsf + OF1O + b*512;
    float s = 0.f;
    #pragma unroll
    for (int i = 0; i < 8; ++i){ int k = lane + (i << 6); s = fmaf(of1[k], wg1[o*512 + k], s); }
    for (int off = 32; off; off >>= 1) s += __shfl_down(s, off);
    if (lane == 0) out[b*256 + 128 + o] = fmaxf(s + bg1[o], 0.f);
  } else if (wid < 2176){                            // group_output_feature -> feature[:,0:128]
    int o = wid - 2048;
    const float* gr1 = wsf + GR1O;
    float s = 0.f;
    #pragma unroll
    for (int i = 0; i < 8; ++i){ int k = lane + (i << 6); s = fmaf(gr1[k], wgr1[o*512 + k], s); }
    for (int off = 32; off; off >>= 1) s += __shfl_down(s, off);
    if (lane == 0){
      float r = fmaxf(s + bgr1[o], 0.f);
      for (int bb = 0; bb < 16; ++bb) out[bb*256 + o] = r;   // identical across batch
    }
  }
}

extern "C" void kernel_launch(void* const* d_in, const int* in_sizes, int n_in,
                              void* d_out, int out_size, void* d_ws, size_t ws_size,
                              hipStream_t stream)
{
  const float* pts  = (const float*)d_in[0];
  const float* wl0  = (const float*)d_in[1];  const float* bl0 = (const float*)d_in[2];
  const float* wl1  = (const float*)d_in[3];  const float* bl1 = (const float*)d_in[4];
  const float* wl2  = (const float*)d_in[5];  const float* bl2 = (const float*)d_in[6];
  const float* wl3  = (const float*)d_in[7];  const float* bl3 = (const float*)d_in[8];
  const float* wl4  = (const float*)d_in[9];  const float* bl4 = (const float*)d_in[10];
  const float* wg0  = (const float*)d_in[11]; const float* bg0 = (const float*)d_in[12];
  const float* wg1  = (const float*)d_in[13]; const float* bg1 = (const float*)d_in[14];
  const float* wgr0 = (const float*)d_in[15]; const float* bgr0 = (const float*)d_in[16];
  const float* wgr1 = (const float*)d_in[17]; const float* bgr1 = (const float*)d_in[18];
  float* wsf = (float*)d_ws;
  float* out = (float*)d_out;

  // ws-adaptive: pmax P slots (128 KB), gmax G slots (16 KB),
  // Wb fp16x2 (512 KB) + Wb1/2/3 (16+16+32 KB)
  int P, G;
  if      (ws_size >= 2400000) { P = 8; G = 16; }   // 2.09 MB
  else if (ws_size >= 1700000) { P = 4; G = 8;  }   // 1.43 MB
  else if (ws_size >= 1360000) { P = 2; G = 4;  }   // 1.11 MB
  else                         { P = 1; G = 2;  }   // 0.94 MB
  u32 pmax_off = FIXED_BYTES;
  u32 gmax_off = pmax_off + (u32)P * 131072u;
  u32 wb_off   = gmax_off + (u32)G * 16384u;
  u32 wb1_off  = wb_off + 524288u;
  u32 wb2_off  = wb1_off + 16384u;
  u32 wb3_off  = wb2_off + 16384u;

  k_prep<<<dim3(1024), dim3(256), 0, stream>>>(wl0, wl1, wl2, wl3, wl4,
      bl0, bl1, bl2, bl3, bl4, wsf, pmax_off, gmax_off, wb_off, P, G);
  k_main<<<dim3(4096), dim3(256), 0, stream>>>(pts, wsf,
      (const u16b*)((char*)d_ws + wb_off),  (const u16b*)((char*)d_ws + wb1_off),
      (const u16b*)((char*)d_ws + wb2_off), (const u16b*)((char*)d_ws + wb3_off),
      (u64*)((char*)d_ws + pmax_off), (u32*)((char*)d_ws + gmax_off), P-1, G-1);
  k_reduce<<<dim3(80), dim3(256), 0, stream>>>(wsf, out, pmax_off, gmax_off, P, G);
  k_mlp1<<<dim3(2176), dim3(256), 0, stream>>>(wsf, wg0, bg0, wgr0, bgr0);
  k_mlp2<<<dim3(544), dim3(256), 0, stream>>>(wsf, wg1, bg1, wgr1, bgr1, out);
}